// Round 3
// baseline (2943.140 us; speedup 1.0000x reference)
//
#include <hip/hip_runtime.h>
#include <math.h>

#define NB 8
#define NT 1500
#define ND 1536
#define NP 1024
#define NE 192
#define NITER 6
#define NEGINF -1e30f

typedef __attribute__((ext_vector_type(8))) short bf16x8;
typedef __attribute__((ext_vector_type(4))) float f32x4;
typedef __attribute__((ext_vector_type(8))) unsigned short us16x8;

__device__ __forceinline__ unsigned short bf_rne(float x) {
    unsigned u = __float_as_uint(x);
    return (unsigned short)((u + 0x7FFFu + ((u >> 16) & 1u)) >> 16);
}
__device__ __forceinline__ float bf_f(unsigned short u) {
    return __uint_as_float(((unsigned)u) << 16);
}

// ---------------- helpers ----------------
__device__ __forceinline__ float block_reduce_sum(float v, float* red) {
    int tid = threadIdx.x;
    red[tid] = v; __syncthreads();
    for (int s = blockDim.x >> 1; s > 0; s >>= 1) {
        if (tid < s) red[tid] += red[tid + s];
        __syncthreads();
    }
    float r = red[0]; __syncthreads();
    return r;
}

// ---------------- pre-pass kernels ----------------
__global__ void k_colstats(const float* __restrict__ h, float* __restrict__ sum1,
                           float* __restrict__ sum2) {
    int d = blockIdx.x * 256 + threadIdx.x;
    int b = blockIdx.y;
    int t0 = blockIdx.z * 125, t1 = t0 + 125;
    const float* hp = h + (size_t)b * NT * ND + d;
    float s = 0.f, s2 = 0.f;
    for (int t = t0; t < t1; ++t) { float v = hp[(size_t)t * ND]; s += v; s2 += v * v; }
    atomicAdd(&sum1[b * ND + d], s);
    atomicAdd(&sum2[b * ND + d], s2);
}

__global__ void k_stats_fin(float* __restrict__ mu0, float* __restrict__ sig0) {
    int i = blockIdx.x * 256 + threadIdx.x;
    float mu = mu0[i] * (1.f / NT);
    float sec = sig0[i] * (1.f / NT);
    mu0[i] = mu;
    sig0[i] = sqrtf(fmaxf(sec - mu * mu, 1e-8f));
}

__global__ void k_energy(const float* __restrict__ h, float* __restrict__ emask) {
    __shared__ float red[256];
    int t = blockIdx.x, b = blockIdx.y;
    const float* hp = h + ((size_t)b * NT + t) * ND;
    float s = 0.f;
    for (int d = threadIdx.x; d < ND; d += 256) { float v = hp[d]; s += v * v; }
    s = block_reduce_sum(s, red);
    if (threadIdx.x == 0) emask[b * NT + t] = (s * (1.f / ND) > 1e-4f) ? 1.f : 0.f;
}

__global__ void k_w2r(const float* __restrict__ W2, const float* __restrict__ b2,
                      float* __restrict__ w2r, float* __restrict__ b2m) {
    __shared__ float red[256];
    int p = blockIdx.x;
    float s = 0.f;
    if (p < NP) {
        const float* row = W2 + (size_t)p * ND;
        for (int d = threadIdx.x; d < ND; d += 256) s += row[d];
        s = block_reduce_sum(s, red);
        if (threadIdx.x == 0) w2r[p] = s * (1.f / ND);
    } else {
        for (int d = threadIdx.x; d < ND; d += 256) s += b2[d];
        s = block_reduce_sum(s, red);
        if (threadIdx.x == 0) b2m[0] = s * (1.f / ND);
    }
}

__global__ void k_biasb(const float* __restrict__ W1, const float* __restrict__ mu0,
                        const float* __restrict__ sig0, float* __restrict__ biasb) {
    int p = blockIdx.x * 256 + threadIdx.x;
    int d0 = blockIdx.y * 192, d1 = d0 + 192;
    float acc[NB];
#pragma unroll
    for (int b = 0; b < NB; ++b) acc[b] = 0.f;
    for (int d = d0; d < d1; ++d) {
        float wa = W1[(size_t)(ND + d) * NP + p];
        float wb = W1[(size_t)(2 * ND + d) * NP + p];
#pragma unroll
        for (int b = 0; b < NB; ++b)
            acc[b] += mu0[b * ND + d] * wa + sig0[b * ND + d] * wb;
    }
#pragma unroll
    for (int b = 0; b < NB; ++b) atomicAdd(&biasb[b * NP + p], acc[b]);
}

__global__ void k_init(float* __restrict__ C, const float* __restrict__ C0,
                       float* __restrict__ stopf) {
    int d = blockIdx.x * 256 + threadIdx.x;
    int b = blockIdx.y;
    C[b * ND + d] = C0[d];
    if (blockIdx.x == 0 && threadIdx.x == 0) stopf[b] = 0.f;
}

// ---------------- weight split (once): W [K][N] f32 -> tiled swizzled bf16 hi/lo ----------------
__global__ void k_split_w(const float* __restrict__ W, int ldw, int kcnt,
                          unsigned short* __restrict__ th, unsigned short* __restrict__ tl) {
    __shared__ float t[128][33];
    int nt = blockIdx.x, kc = blockIdx.y, tid = threadIdx.x;
    int col = tid & 127, kh = tid >> 7;
    const float* wp = W + (size_t)(kc * 32 + kh) * ldw + nt * 128 + col;
#pragma unroll
    for (int i = 0; i < 16; ++i)
        t[col][kh + 2 * i] = wp[(size_t)(2 * i) * ldw];
    __syncthreads();
    int r = tid >> 1;
    int swz = (r >> 1) & 3;
    size_t tb = ((size_t)nt * kcnt + kc) * 4096;
#pragma unroll
    for (int j = 0; j < 2; ++j) {
        int so = (tid & 1) * 2 + j;
        int s = so ^ swz;
        us16x8 hv, lv;
#pragma unroll
        for (int q = 0; q < 8; ++q) {
            float x = t[r][s * 8 + q];
            unsigned short hh = bf_rne(x);
            hv[q] = hh;
            lv[q] = bf_rne(x - bf_f(hh));
        }
        *(us16x8*)&th[tb + r * 32 + so * 8] = hv;
        *(us16x8*)&tl[tb + r * 32 + so * 8] = lv;
    }
}

// ---------------- per-iter fused: relu(base+cvec) -> hi tile, + att partial sums ----------------
// grid (12, 32, NB), block 256
__global__ void k_relu_att(const float* __restrict__ base, const float* __restrict__ cvec,
                           const float* __restrict__ w2r, unsigned short* __restrict__ th,
                           float* __restrict__ att) {
    int tr = blockIdx.x, kc = blockIdx.y, b = blockIdx.z;
    int tid = threadIdx.x;
    int r = tid >> 1, quad = tid & 1;
    int row = tr * 128 + r;
    bool ok = row < NT;
    size_t tb = ((size_t)(b * 12 + tr) * 32 + kc) * 4096;
    const float* bp = base + ((size_t)b * NT + row) * NP + kc * 32 + quad * 16;
    const float* cv = cvec + b * NP + kc * 32 + quad * 16;
    const float* wr = w2r + kc * 32 + quad * 16;
    int swz = (r >> 1) & 3;
    float asum = 0.f;
#pragma unroll
    for (int half = 0; half < 2; ++half) {
        us16x8 hv;
#pragma unroll
        for (int j = 0; j < 2; ++j) {
            float x0 = 0.f, x1 = 0.f, x2 = 0.f, x3 = 0.f;
            if (ok) {
                float4 v = *(const float4*)(bp + half * 8 + j * 4);
                float4 c4 = *(const float4*)(cv + half * 8 + j * 4);
                float4 w4 = *(const float4*)(wr + half * 8 + j * 4);
                x0 = fmaxf(v.x + c4.x, 0.f); x1 = fmaxf(v.y + c4.y, 0.f);
                x2 = fmaxf(v.z + c4.z, 0.f); x3 = fmaxf(v.w + c4.w, 0.f);
                asum += x0 * w4.x + x1 * w4.y + x2 * w4.z + x3 * w4.w;
            }
            hv[j * 4 + 0] = bf_rne(x0); hv[j * 4 + 1] = bf_rne(x1);
            hv[j * 4 + 2] = bf_rne(x2); hv[j * 4 + 3] = bf_rne(x3);
        }
        int off = r * 32 + (((quad * 2 + half) ^ swz) << 3);
        *(us16x8*)&th[tb + off] = hv;
    }
    asum += __shfl_xor(asum, 1);
    if (ok && quad == 0) atomicAdd(&att[b * NT + row], asum);
}

// ---------------- MFMA GEMM, 2-phase double-buffered ----------------
// RELU=true : A = pre-split relu hi tiles, 2-term (ah*bh + ah*bl), K=1024, N=1536;
//             epilogue accumulates mu_p/s2p/zA/Ah
// RELU=false: A = h (f32, on-the-fly hi/lo split), 3-term, K=1536, N=1024;
//             epilogue writes base(+biasb)
template <bool RELU>
__global__ __launch_bounds__(256) void k_gemm_mfma(
    const float* __restrict__ hsrc, const unsigned short* __restrict__ at_h,
    const unsigned short* __restrict__ bt_h, const unsigned short* __restrict__ bt_l,
    const float* __restrict__ biasv, float* __restrict__ Out,
    const float* __restrict__ Aw, float* __restrict__ mup, float* __restrict__ s2p,
    float* __restrict__ zab, float* __restrict__ ahb) {
    constexpr int K = RELU ? NP : ND;
    constexpr int KC = K / 32;
    __shared__ unsigned short As_h[2][4096];
    __shared__ unsigned short As_l[2][RELU ? 16 : 4096];
    __shared__ unsigned short Bs_h[2][4096];
    __shared__ unsigned short Bs_l[2][4096];
    int b = blockIdx.z, tr = blockIdx.x, nt = blockIdx.y;
    int tid = threadIdx.x;
    int lane = tid & 63, w = tid >> 6;
    int wr = w >> 1, wc = w & 1;
    int l15 = lane & 15, kg = lane >> 4;
    int sw = (l15 >> 1) & 3;
    f32x4 acc[4][4];
#pragma unroll
    for (int m = 0; m < 4; ++m)
#pragma unroll
        for (int n = 0; n < 4; ++n) acc[m][n] = (f32x4){0.f, 0.f, 0.f, 0.f};
    int aoff[4], boff[4];
#pragma unroll
    for (int m = 0; m < 4; ++m) aoff[m] = (wr * 64 + m * 16 + l15) * 32 + ((kg ^ sw) << 3);
#pragma unroll
    for (int n = 0; n < 4; ++n) boff[n] = (wc * 64 + n * 16 + l15) * 32 + ((kg ^ sw) << 3);

    const unsigned short* gbh = bt_h + ((size_t)nt * KC) * 4096 + lane * 8;
    const unsigned short* gbl = bt_l + ((size_t)nt * KC) * 4096 + lane * 8;
    const unsigned short* ga = RELU ? (at_h + ((size_t)(b * 12 + tr) * KC) * 4096 + lane * 8)
                                    : nullptr;

    // on-the-fly A (base path)
    int r2 = tid >> 1, quad = tid & 1;
    int arow = tr * 128 + r2;
    bool aok = arow < NT;
    int aswz = (r2 >> 1) & 3;
    const float* hp = hsrc + ((size_t)b * NT + arow) * ND + quad * 16;

    auto stage = [&](int buf, int kc) {
        if (RELU) {
            // 24 segments: As_h(8) Bs_h(8) Bs_l(8); 6 per wave
#pragma unroll
            for (int c = 0; c < 6; ++c) {
                int seg = w * 6 + c;
                int bufid = seg >> 3, part = seg & 7;
                const unsigned short* src =
                    (bufid == 0 ? ga : bufid == 1 ? gbh : gbl) + (size_t)kc * 4096 + part * 512;
                unsigned short* dst =
                    (bufid == 0 ? &As_h[buf][0] : bufid == 1 ? &Bs_h[buf][0] : &Bs_l[buf][0]) +
                    part * 512;
                __builtin_amdgcn_global_load_lds(src, dst, 16, 0, 0);
            }
        } else {
            // 16 segments: Bs_h(8) Bs_l(8); 4 per wave
#pragma unroll
            for (int c = 0; c < 4; ++c) {
                int seg = w * 4 + c;
                int part = seg & 7;
                const unsigned short* src =
                    ((seg >> 3) == 0 ? gbh : gbl) + (size_t)kc * 4096 + part * 512;
                unsigned short* dst =
                    ((seg >> 3) == 0 ? &Bs_h[buf][0] : &Bs_l[buf][0]) + part * 512;
                __builtin_amdgcn_global_load_lds(src, dst, 16, 0, 0);
            }
        }
    };
    auto loadA = [&](int kc, float4* hv) {
#pragma unroll
        for (int j = 0; j < 4; ++j) {
            hv[j] = aok ? *(const float4*)(hp + kc * 32 + j * 4)
                        : make_float4(0.f, 0.f, 0.f, 0.f);
        }
    };
    auto writeA = [&](int buf, const float4* hv) {
#pragma unroll
        for (int half = 0; half < 2; ++half) {
            us16x8 hi, lo;
#pragma unroll
            for (int j = 0; j < 2; ++j) {
                float4 v = hv[half * 2 + j];
                float x[4] = {v.x, v.y, v.z, v.w};
#pragma unroll
                for (int q = 0; q < 4; ++q) {
                    unsigned short hh = bf_rne(x[q]);
                    hi[j * 4 + q] = hh;
                    lo[j * 4 + q] = bf_rne(x[q] - bf_f(hh));
                }
            }
            int off = r2 * 32 + (((quad * 2 + half) ^ aswz) << 3);
            *(us16x8*)&As_h[buf][off] = hi;
            *(us16x8*)&As_l[buf][off] = lo;
        }
    };

    // prologue
    stage(0, 0);
    if (!RELU) {
        float4 hv[4];
        loadA(0, hv);
        writeA(0, hv);
    }
    __syncthreads();
    int cur = 0;
    for (int kc = 0; kc < KC; ++kc) {
        bool np = kc + 1 < KC;
        float4 hv[4];
        if (np) {
            stage(cur ^ 1, kc + 1);
            if (!RELU) loadA(kc + 1, hv);
        }
        bf16x8 ahf[4], alf[4];
#pragma unroll
        for (int m = 0; m < 4; ++m) {
            ahf[m] = *(const bf16x8*)&As_h[cur][aoff[m]];
            if (!RELU) alf[m] = *(const bf16x8*)&As_l[cur][aoff[m]];
        }
#pragma unroll
        for (int n = 0; n < 4; ++n) {
            bf16x8 bh = *(const bf16x8*)&Bs_h[cur][boff[n]];
            bf16x8 bl = *(const bf16x8*)&Bs_l[cur][boff[n]];
#pragma unroll
            for (int m = 0; m < 4; ++m) {
                acc[m][n] = __builtin_amdgcn_mfma_f32_16x16x32_bf16(ahf[m], bh, acc[m][n], 0, 0, 0);
                acc[m][n] = __builtin_amdgcn_mfma_f32_16x16x32_bf16(ahf[m], bl, acc[m][n], 0, 0, 0);
                if (!RELU)
                    acc[m][n] = __builtin_amdgcn_mfma_f32_16x16x32_bf16(alf[m], bh, acc[m][n], 0, 0, 0);
            }
        }
        if (np && !RELU) writeA(cur ^ 1, hv);
        __syncthreads();
        cur ^= 1;
    }

    int rowb = tr * 128 + wr * 64 + (kg << 2);
    int colb = nt * 128 + wc * 64 + l15;
    if (RELU) {
        float b2c[4];
#pragma unroll
        for (int n = 0; n < 4; ++n) b2c[n] = biasv[colb + n * 16];
        float pm[4] = {0, 0, 0, 0}, ps2[4] = {0, 0, 0, 0}, pza[4] = {0, 0, 0, 0}, pah[4] = {0, 0, 0, 0};
#pragma unroll
        for (int m = 0; m < 4; ++m) {
#pragma unroll
            for (int q = 0; q < 4; ++q) {
                int row = rowb + m * 16 + q;
                bool ok = row < NT;
                int rowc = ok ? row : (NT - 1);
                float okf = ok ? 1.f : 0.f;
                float a = Aw[b * NT + rowc] * okf;
                const float* hrow = hsrc + ((size_t)b * NT + rowc) * ND;
#pragma unroll
                for (int n = 0; n < 4; ++n) {
                    float hv = hrow[colb + n * 16] * okf;
                    float o2 = acc[m][n][q] + b2c[n];
                    pm[n] = fmaf(o2, hv, pm[n]);
                    ps2[n] = fmaf(o2 * hv, hv, ps2[n]);
                    pza[n] = fmaf(a, o2, pza[n]);
                    pah[n] = fmaf(a, hv, pah[n]);
                }
            }
        }
#pragma unroll
        for (int n = 0; n < 4; ++n) {
            pm[n] += __shfl_xor(pm[n], 16); pm[n] += __shfl_xor(pm[n], 32);
            ps2[n] += __shfl_xor(ps2[n], 16); ps2[n] += __shfl_xor(ps2[n], 32);
            pza[n] += __shfl_xor(pza[n], 16); pza[n] += __shfl_xor(pza[n], 32);
            pah[n] += __shfl_xor(pah[n], 16); pah[n] += __shfl_xor(pah[n], 32);
            if (kg == 0) {
                int col = colb + n * 16;
                atomicAdd(&mup[b * ND + col], pm[n]);
                atomicAdd(&s2p[b * ND + col], ps2[n]);
                atomicAdd(&zab[b * ND + col], pza[n]);
                atomicAdd(&ahb[b * ND + col], pah[n]);
            }
        }
    } else {
#pragma unroll
        for (int m = 0; m < 4; ++m)
#pragma unroll
            for (int q = 0; q < 4; ++q) {
                int row = rowb + m * 16 + q;
                if (row < NT) {
                    float* orow = Out + ((size_t)b * NT + row) * NP;
#pragma unroll
                    for (int n = 0; n < 4; ++n)
                        orow[colb + n * 16] = acc[m][n][q] + biasv[b * NP + colb + n * 16];
                }
            }
    }
}

// ---------------- per-iteration small kernels ----------------
// grid (4, 32), block 256
__global__ void k_cvec(const float* __restrict__ C, const float* __restrict__ Wc,
                       float* __restrict__ cvec) {
    int p = blockIdx.x * 256 + threadIdx.x;
    int d0 = blockIdx.y * 48, d1 = d0 + 48;
    float acc[NB];
#pragma unroll
    for (int b = 0; b < NB; ++b) acc[b] = 0.f;
    for (int d = d0; d < d1; ++d) {
        float wc = Wc[(size_t)d * NP + p];
#pragma unroll
        for (int b = 0; b < NB; ++b) acc[b] += C[b * ND + d] * wc;
    }
#pragma unroll
    for (int b = 0; b < NB; ++b) atomicAdd(&cvec[b * NP + p], acc[b]);
}

__global__ void k_softmax(const float* __restrict__ att, const float* __restrict__ emask,
                          const float* __restrict__ b2m, float* __restrict__ A) {
    __shared__ float red[256];
    int b = blockIdx.x, tid = threadIdx.x;
    float bm = b2m[0];
    const float* x = att + (size_t)b * NT;
    const float* em = emask + (size_t)b * NT;
    float* a = A + (size_t)b * NT;
    float mx = -3.4e38f;
    for (int t = tid; t < NT; t += 256) {
        float v = (em[t] > 0.5f) ? x[t] + bm : NEGINF;
        mx = fmaxf(mx, v);
    }
    red[tid] = mx; __syncthreads();
    for (int s = 128; s > 0; s >>= 1) {
        if (tid < s) red[tid] = fmaxf(red[tid], red[tid + s]);
        __syncthreads();
    }
    mx = red[0]; __syncthreads();
    float sm = 0.f;
    for (int t = tid; t < NT; t += 256) {
        float v = (em[t] > 0.5f) ? x[t] + bm : NEGINF;
        float e = expf(v - mx); a[t] = e; sm += e;
    }
    float s1 = block_reduce_sum(sm, red);
    float inv1 = 1.f / s1;
    float sm2 = 0.f;
    for (int t = tid; t < NT; t += 256) { float v = a[t] * inv1; a[t] = v; sm2 += v; }
    float s2 = block_reduce_sum(sm2, red);
    float inv2 = 1.f / (s2 + 1e-8f);
    for (int t = tid; t < NT; t += 256) a[t] *= inv2;
}

// fused sigma + emb + embnorm + C-update + stop; grid NB, block 256
__global__ void k_tail(const float* __restrict__ red4, const float* __restrict__ w0,
                       const float* __restrict__ b0, const float* __restrict__ Wstop,
                       const float* __restrict__ bstop, const float* __restrict__ thr,
                       float* __restrict__ Cb, float* __restrict__ stopf,
                       float* __restrict__ Eout, float* __restrict__ Pout, int iter) {
    __shared__ float mus[ND], sgs[ND];
    __shared__ float red[256];
    int b = blockIdx.x, tid = threadIdx.x;
    const float* mup = red4 + (size_t)b * ND;
    const float* s2p = red4 + (size_t)NB * ND + b * ND;
    const float* Ahb = red4 + (size_t)2 * NB * ND + b * ND;
    const float* zAb = red4 + (size_t)3 * NB * ND + b * ND;
    for (int d = tid; d < ND; d += 256) {
        float mu = mup[d];
        mus[d] = mu;
        sgs[d] = sqrtf(fmaxf(s2p[d] - mu * mu, 1e-8f));
    }
    __syncthreads();
    float emb = 0.f;
    if (tid < NE) {
#pragma unroll 4
        for (int d = 0; d < ND; ++d)
            emb += mus[d] * w0[(size_t)d * NE + tid] + sgs[d] * w0[(size_t)(ND + d) * NE + tid];
        emb += b0[tid];
    }
    float nrm = block_reduce_sum((tid < NE) ? emb * emb : 0.f, red);
    float sc = 1.f / fmaxf(sqrtf(nrm), 1e-12f);
    if (tid < NE) Eout[((size_t)b * NITER + iter) * NE + tid] = emb * sc;
    float active = (stopf[b] > 0.5f) ? 0.f : 1.f;
    float dsum = 0.f;
    for (int d = tid; d < ND; d += 256) {
        float Cn = Cb[b * ND + d] + active * (Ahb[d] * (1.f / NT));
        Cb[b * ND + d] = Cn;
        dsum += zAb[d] * Wstop[d] + Cn * Wstop[ND + d];
    }
    float s = block_reduce_sum(dsum, red);
    if (tid == 0) {
        float logit = s + bstop[0];
        float p = 1.f / (1.f + expf(-logit));
        Pout[b * NITER + iter] = p;
        if (p < thr[0]) stopf[b] = 1.f;
    }
}

__global__ void k_mask(float* __restrict__ Eout, const float* __restrict__ Pout,
                       const float* __restrict__ thr) {
    __shared__ float run;
    int b = blockIdx.x, tid = threadIdx.x;
    if (tid == 0) run = 1.f;
    __syncthreads();
    for (int j = 0; j < NITER; ++j) {
        if (tid == 0) { if (Pout[b * NITER + j] < thr[0]) run = 0.f; }
        __syncthreads();
        Eout[((size_t)b * NITER + j) * NE + tid] *= run;
        __syncthreads();
    }
}

// ---------------- launch ----------------
extern "C" void kernel_launch(void* const* d_in, const int* in_sizes, int n_in,
                              void* d_out, int out_size, void* d_ws, size_t ws_size,
                              hipStream_t stream) {
    const float* h = (const float*)d_in[0];
    const float* W1 = (const float*)d_in[1];
    const float* Wc = (const float*)d_in[2];
    const float* W2 = (const float*)d_in[3];
    const float* b2 = (const float*)d_in[4];
    const float* w0 = (const float*)d_in[5];
    const float* b0 = (const float*)d_in[6];
    const float* Wstop = (const float*)d_in[7];
    const float* bstop = (const float*)d_in[8];
    const float* thr = (const float*)d_in[9];
    const float* C0 = (const float*)d_in[10];

    float* Eout = (float*)d_out;
    float* Pout = Eout + (size_t)NB * NITER * NE;

    char* wsb = (char*)d_ws;
    size_t off = 0;
    auto alloc = [&](size_t bytes) -> void* {
        void* p = wsb + off; off += (bytes + 15) & ~(size_t)15; return p;
    };

    float* base = (float*)alloc((size_t)NB * NT * NP * 4);
    unsigned short* rel_h = (unsigned short*)alloc((size_t)NB * 12 * 32 * 4096 * 2);
    unsigned short* w1t_h = (unsigned short*)alloc((size_t)8 * 48 * 4096 * 2);
    unsigned short* w1t_l = (unsigned short*)alloc((size_t)8 * 48 * 4096 * 2);
    unsigned short* w2t_h = (unsigned short*)alloc((size_t)12 * 32 * 4096 * 2);
    unsigned short* w2t_l = (unsigned short*)alloc((size_t)12 * 32 * 4096 * 2);
    float* mu0 = (float*)alloc((size_t)2 * NB * ND * 4);  // mu0 + sig0 contiguous
    float* sig0 = mu0 + NB * ND;
    float* emask = (float*)alloc(NB * NT * 4);
    float* biasb = (float*)alloc(NB * NP * 4);
    float* w2r = (float*)alloc(NP * 4);
    float* b2m = (float*)alloc(16);
    // zero-region: cvec | att | red4 (contiguous, one memset per iteration)
    float* cvec = (float*)alloc(((size_t)NB * NP + NB * NT + 4 * NB * ND) * 4);
    float* att = cvec + NB * NP;
    float* red4 = att + NB * NT;
    float* mup = red4;
    float* s2p = red4 + NB * ND;
    float* Ahb = red4 + 2 * NB * ND;
    float* zAb = red4 + 3 * NB * ND;
    float* Abuf = (float*)alloc(NB * NT * 4);
    float* Cb = (float*)alloc(NB * ND * 4);
    float* stopf = (float*)alloc(32);
    size_t zero_bytes = ((size_t)NB * NP + NB * NT + 4 * NB * ND) * 4;

    // ---- pre-pass ----
    hipMemsetAsync(mu0, 0, (size_t)2 * NB * ND * 4, stream);
    hipMemsetAsync(biasb, 0, (size_t)NB * NP * 4, stream);
    k_colstats<<<dim3(ND / 256, NB, 12), 256, 0, stream>>>(h, mu0, sig0);
    k_stats_fin<<<dim3(NB * ND / 256), 256, 0, stream>>>(mu0, sig0);
    k_energy<<<dim3(NT, NB), 256, 0, stream>>>(h, emask);
    k_w2r<<<dim3(NP + 1), 256, 0, stream>>>(W2, b2, w2r, b2m);
    k_biasb<<<dim3(NP / 256, 8), 256, 0, stream>>>(W1, mu0, sig0, biasb);
    k_split_w<<<dim3(8, 48), 256, 0, stream>>>(W1, NP, 48, w1t_h, w1t_l);
    k_split_w<<<dim3(12, 32), 256, 0, stream>>>(W2, ND, 32, w2t_h, w2t_l);
    k_gemm_mfma<false><<<dim3(12, 8, NB), 256, 0, stream>>>(
        h, nullptr, w1t_h, w1t_l, biasb, base, nullptr, nullptr, nullptr, nullptr, nullptr);
    k_init<<<dim3(ND / 256, NB), 256, 0, stream>>>(Cb, C0, stopf);

    // ---- iterations ----
    for (int i = 0; i < NITER; ++i) {
        hipMemsetAsync(cvec, 0, zero_bytes, stream);
        k_cvec<<<dim3(4, 32), 256, 0, stream>>>(Cb, Wc, cvec);
        k_relu_att<<<dim3(12, 32, NB), 256, 0, stream>>>(base, cvec, w2r, rel_h, att);
        k_softmax<<<dim3(NB), 256, 0, stream>>>(att, emask, b2m, Abuf);
        k_gemm_mfma<true><<<dim3(12, 12, NB), 256, 0, stream>>>(
            h, rel_h, w2t_h, w2t_l, b2, nullptr, Abuf, mup, s2p, zAb, Ahb);
        k_tail<<<dim3(NB), 256, 0, stream>>>(red4, w0, b0, Wstop, bstop, thr,
                                             Cb, stopf, Eout, Pout, i);
    }
    k_mask<<<dim3(NB), 192, 0, stream>>>(Eout, Pout, thr);
}

// Round 4
// 1975.525 us; speedup vs baseline: 1.4898x; 1.4898x over previous
//
#include <hip/hip_runtime.h>
#include <math.h>

#define NB 8
#define NT 1500
#define ND 1536
#define NP 1024
#define NE 192
#define NITER 6
#define NEGINF -1e30f

typedef __attribute__((ext_vector_type(8))) short bf16x8;
typedef __attribute__((ext_vector_type(4))) float f32x4;
typedef __attribute__((ext_vector_type(8))) unsigned short us16x8;

__device__ __forceinline__ unsigned short bf_rne(float x) {
    unsigned u = __float_as_uint(x);
    return (unsigned short)((u + 0x7FFFu + ((u >> 16) & 1u)) >> 16);
}
__device__ __forceinline__ float bf_f(unsigned short u) {
    return __uint_as_float(((unsigned)u) << 16);
}

// ---------------- helpers ----------------
__device__ __forceinline__ float block_reduce_sum(float v, float* red) {
    int tid = threadIdx.x;
    red[tid] = v; __syncthreads();
    for (int s = blockDim.x >> 1; s > 0; s >>= 1) {
        if (tid < s) red[tid] += red[tid + s];
        __syncthreads();
    }
    float r = red[0]; __syncthreads();
    return r;
}

// ---------------- pre-pass kernels ----------------
__global__ void k_colstats(const float* __restrict__ h, float* __restrict__ sum1,
                           float* __restrict__ sum2) {
    int d = blockIdx.x * 256 + threadIdx.x;
    int b = blockIdx.y;
    int t0 = blockIdx.z * 125, t1 = t0 + 125;
    const float* hp = h + (size_t)b * NT * ND + d;
    float s = 0.f, s2 = 0.f;
    for (int t = t0; t < t1; ++t) { float v = hp[(size_t)t * ND]; s += v; s2 += v * v; }
    atomicAdd(&sum1[b * ND + d], s);
    atomicAdd(&sum2[b * ND + d], s2);
}

__global__ void k_stats_fin(float* __restrict__ mu0, float* __restrict__ sig0) {
    int i = blockIdx.x * 256 + threadIdx.x;
    float mu = mu0[i] * (1.f / NT);
    float sec = sig0[i] * (1.f / NT);
    mu0[i] = mu;
    sig0[i] = sqrtf(fmaxf(sec - mu * mu, 1e-8f));
}

__global__ void k_energy(const float* __restrict__ h, float* __restrict__ emask) {
    __shared__ float red[256];
    int t = blockIdx.x, b = blockIdx.y;
    const float* hp = h + ((size_t)b * NT + t) * ND;
    float s = 0.f;
    for (int d = threadIdx.x; d < ND; d += 256) { float v = hp[d]; s += v * v; }
    s = block_reduce_sum(s, red);
    if (threadIdx.x == 0) emask[b * NT + t] = (s * (1.f / ND) > 1e-4f) ? 1.f : 0.f;
}

__global__ void k_w2r(const float* __restrict__ W2, const float* __restrict__ b2,
                      float* __restrict__ w2r, float* __restrict__ b2m) {
    __shared__ float red[256];
    int p = blockIdx.x;
    float s = 0.f;
    if (p < NP) {
        const float* row = W2 + (size_t)p * ND;
        for (int d = threadIdx.x; d < ND; d += 256) s += row[d];
        s = block_reduce_sum(s, red);
        if (threadIdx.x == 0) w2r[p] = s * (1.f / ND);
    } else {
        for (int d = threadIdx.x; d < ND; d += 256) s += b2[d];
        s = block_reduce_sum(s, red);
        if (threadIdx.x == 0) b2m[0] = s * (1.f / ND);
    }
}

__global__ void k_biasb(const float* __restrict__ W1, const float* __restrict__ mu0,
                        const float* __restrict__ sig0, float* __restrict__ biasb) {
    int p = blockIdx.x * 256 + threadIdx.x;
    int d0 = blockIdx.y * 192, d1 = d0 + 192;
    float acc[NB];
#pragma unroll
    for (int b = 0; b < NB; ++b) acc[b] = 0.f;
    for (int d = d0; d < d1; ++d) {
        float wa = W1[(size_t)(ND + d) * NP + p];
        float wb = W1[(size_t)(2 * ND + d) * NP + p];
#pragma unroll
        for (int b = 0; b < NB; ++b)
            acc[b] += mu0[b * ND + d] * wa + sig0[b * ND + d] * wb;
    }
#pragma unroll
    for (int b = 0; b < NB; ++b) atomicAdd(&biasb[b * NP + p], acc[b]);
}

__global__ void k_init(float* __restrict__ C, const float* __restrict__ C0,
                       float* __restrict__ stopf) {
    int d = blockIdx.x * 256 + threadIdx.x;
    int b = blockIdx.y;
    C[b * ND + d] = C0[d];
    if (blockIdx.x == 0 && threadIdx.x == 0) stopf[b] = 0.f;
}

// ---------------- weight split (once): W [K][N] f32 -> tiled swizzled bf16 hi/lo ----------------
__global__ void k_split_w(const float* __restrict__ W, int ldw, int kcnt,
                          unsigned short* __restrict__ th, unsigned short* __restrict__ tl) {
    __shared__ float t[128][33];
    int nt = blockIdx.x, kc = blockIdx.y, tid = threadIdx.x;
    int col = tid & 127, kh = tid >> 7;
    const float* wp = W + (size_t)(kc * 32 + kh) * ldw + nt * 128 + col;
#pragma unroll
    for (int i = 0; i < 16; ++i)
        t[col][kh + 2 * i] = wp[(size_t)(2 * i) * ldw];
    __syncthreads();
    int r = tid >> 1;
    int swz = (r >> 1) & 3;
    size_t tb = ((size_t)nt * kcnt + kc) * 4096;
#pragma unroll
    for (int j = 0; j < 2; ++j) {
        int so = (tid & 1) * 2 + j;
        int s = so ^ swz;
        us16x8 hv, lv;
#pragma unroll
        for (int q = 0; q < 8; ++q) {
            float x = t[r][s * 8 + q];
            unsigned short hh = bf_rne(x);
            hv[q] = hh;
            lv[q] = bf_rne(x - bf_f(hh));
        }
        *(us16x8*)&th[tb + r * 32 + so * 8] = hv;
        *(us16x8*)&tl[tb + r * 32 + so * 8] = lv;
    }
}

// ---------------- per-iter fused: relu(base+cvec) -> hi tile, + att partial sums ----------------
// grid (12, 32, NB), block 256
__global__ void k_relu_att(const float* __restrict__ base, const float* __restrict__ cvec,
                           const float* __restrict__ w2r, unsigned short* __restrict__ th,
                           float* __restrict__ att) {
    int tr = blockIdx.x, kc = blockIdx.y, b = blockIdx.z;
    int tid = threadIdx.x;
    int r = tid >> 1, quad = tid & 1;
    int row = tr * 128 + r;
    bool ok = row < NT;
    size_t tb = ((size_t)(b * 12 + tr) * 32 + kc) * 4096;
    const float* bp = base + ((size_t)b * NT + row) * NP + kc * 32 + quad * 16;
    const float* cv = cvec + b * NP + kc * 32 + quad * 16;
    const float* wr = w2r + kc * 32 + quad * 16;
    int swz = (r >> 1) & 3;
    float asum = 0.f;
#pragma unroll
    for (int half = 0; half < 2; ++half) {
        us16x8 hv;
#pragma unroll
        for (int j = 0; j < 2; ++j) {
            float x0 = 0.f, x1 = 0.f, x2 = 0.f, x3 = 0.f;
            if (ok) {
                float4 v = *(const float4*)(bp + half * 8 + j * 4);
                float4 c4 = *(const float4*)(cv + half * 8 + j * 4);
                float4 w4 = *(const float4*)(wr + half * 8 + j * 4);
                x0 = fmaxf(v.x + c4.x, 0.f); x1 = fmaxf(v.y + c4.y, 0.f);
                x2 = fmaxf(v.z + c4.z, 0.f); x3 = fmaxf(v.w + c4.w, 0.f);
                asum += x0 * w4.x + x1 * w4.y + x2 * w4.z + x3 * w4.w;
            }
            hv[j * 4 + 0] = bf_rne(x0); hv[j * 4 + 1] = bf_rne(x1);
            hv[j * 4 + 2] = bf_rne(x2); hv[j * 4 + 3] = bf_rne(x3);
        }
        int off = r * 32 + (((quad * 2 + half) ^ swz) << 3);
        *(us16x8*)&th[tb + off] = hv;
    }
    asum += __shfl_xor(asum, 1);
    if (ok && quad == 0) atomicAdd(&att[b * NT + row], asum);
}

// ---------------- MFMA GEMM, single-buffered (round-2 proven structure) ----------------
// RELU=true : A = pre-split relu hi tiles, 2-term (ah*bh + ah*bl), K=1024, N=1536;
//             epilogue accumulates mu_p/s2p/zA/Ah
// RELU=false: A = h (f32, on-the-fly hi/lo split), 3-term, K=1536, N=1024;
//             epilogue writes base(+biasb)
template <bool RELU>
__global__ __launch_bounds__(256, 4) void k_gemm_mfma(
    const float* __restrict__ hsrc, const unsigned short* __restrict__ at_h,
    const unsigned short* __restrict__ bt_h, const unsigned short* __restrict__ bt_l,
    const float* __restrict__ biasv, float* __restrict__ Out,
    const float* __restrict__ Aw, float* __restrict__ mup, float* __restrict__ s2p,
    float* __restrict__ zab, float* __restrict__ ahb) {
    constexpr int K = RELU ? NP : ND;
    constexpr int KC = K / 32;
    __shared__ unsigned short As_h[4096];
    __shared__ unsigned short As_l[RELU ? 16 : 4096];
    __shared__ unsigned short Bs_h[4096];
    __shared__ unsigned short Bs_l[4096];
    int b = blockIdx.z, tr = blockIdx.x, nt = blockIdx.y;
    int tid = threadIdx.x;
    int lane = tid & 63, w = tid >> 6;
    int wr = w >> 1, wc = w & 1;
    int l15 = lane & 15, kg = lane >> 4;
    int sw = (l15 >> 1) & 3;
    f32x4 acc[4][4];
#pragma unroll
    for (int m = 0; m < 4; ++m)
#pragma unroll
        for (int n = 0; n < 4; ++n) acc[m][n] = (f32x4){0.f, 0.f, 0.f, 0.f};
    int aoff[4], boff[4];
#pragma unroll
    for (int m = 0; m < 4; ++m) aoff[m] = (wr * 64 + m * 16 + l15) * 32 + ((kg ^ sw) << 3);
#pragma unroll
    for (int n = 0; n < 4; ++n) boff[n] = (wc * 64 + n * 16 + l15) * 32 + ((kg ^ sw) << 3);

    const unsigned short* gbh = bt_h + ((size_t)nt * KC) * 4096 + lane * 8;
    const unsigned short* gbl = bt_l + ((size_t)nt * KC) * 4096 + lane * 8;
    const unsigned short* ga = RELU ? (at_h + ((size_t)(b * 12 + tr) * KC) * 4096 + lane * 8)
                                    : nullptr;

    // on-the-fly A (base path)
    int r2 = tid >> 1, quad = tid & 1;
    int arow = tr * 128 + r2;
    bool aok = arow < NT;
    int aswz = (r2 >> 1) & 3;
    const float* hp = hsrc + ((size_t)b * NT + arow) * ND + quad * 16;

    for (int kc = 0; kc < KC; ++kc) {
        if (RELU) {
            // 24 segments: As_h(8) Bs_h(8) Bs_l(8); 6 per wave
#pragma unroll
            for (int c = 0; c < 6; ++c) {
                int seg = w * 6 + c;
                int bufid = seg >> 3, part = seg & 7;
                const unsigned short* src =
                    (bufid == 0 ? ga : bufid == 1 ? gbh : gbl) + (size_t)kc * 4096 + part * 512;
                unsigned short* dst =
                    (bufid == 0 ? &As_h[0] : bufid == 1 ? &Bs_h[0] : &Bs_l[0]) + part * 512;
                __builtin_amdgcn_global_load_lds(src, dst, 16, 0, 0);
            }
        } else {
            // 16 segments: Bs_h(8) Bs_l(8); 4 per wave
#pragma unroll
            for (int c = 0; c < 4; ++c) {
                int seg = w * 4 + c;
                int part = seg & 7;
                const unsigned short* src =
                    ((seg >> 3) == 0 ? gbh : gbl) + (size_t)kc * 4096 + part * 512;
                unsigned short* dst = ((seg >> 3) == 0 ? &Bs_h[0] : &Bs_l[0]) + part * 512;
                __builtin_amdgcn_global_load_lds(src, dst, 16, 0, 0);
            }
            // A: f32 load, split to hi/lo, LDS write
#pragma unroll
            for (int i = 0; i < 4; ++i) {
                int kk = quad * 16 + i * 4;
                float x0 = 0.f, x1 = 0.f, x2 = 0.f, x3 = 0.f;
                if (aok) {
                    float4 v = *(const float4*)(hp + kc * 32 + i * 4);
                    x0 = v.x; x1 = v.y; x2 = v.z; x3 = v.w;
                }
                unsigned short h0 = bf_rne(x0), h1 = bf_rne(x1), h2 = bf_rne(x2), h3 = bf_rne(x3);
                int off = r2 * 32 + (((kk >> 3) ^ aswz) << 3) + (kk & 7);
                *(ushort4*)&As_h[off] = make_ushort4(h0, h1, h2, h3);
                *(ushort4*)&As_l[off] = make_ushort4(bf_rne(x0 - bf_f(h0)), bf_rne(x1 - bf_f(h1)),
                                                     bf_rne(x2 - bf_f(h2)), bf_rne(x3 - bf_f(h3)));
            }
        }
        __syncthreads();
        bf16x8 ahf[4], alf[4];
#pragma unroll
        for (int m = 0; m < 4; ++m) {
            ahf[m] = *(const bf16x8*)&As_h[aoff[m]];
            if (!RELU) alf[m] = *(const bf16x8*)&As_l[aoff[m]];
        }
#pragma unroll
        for (int n = 0; n < 4; ++n) {
            bf16x8 bh = *(const bf16x8*)&Bs_h[boff[n]];
            bf16x8 bl = *(const bf16x8*)&Bs_l[boff[n]];
#pragma unroll
            for (int m = 0; m < 4; ++m) {
                acc[m][n] = __builtin_amdgcn_mfma_f32_16x16x32_bf16(ahf[m], bh, acc[m][n], 0, 0, 0);
                acc[m][n] = __builtin_amdgcn_mfma_f32_16x16x32_bf16(ahf[m], bl, acc[m][n], 0, 0, 0);
                if (!RELU)
                    acc[m][n] = __builtin_amdgcn_mfma_f32_16x16x32_bf16(alf[m], bh, acc[m][n], 0, 0, 0);
            }
        }
        __syncthreads();
    }

    int rowb = tr * 128 + wr * 64 + (kg << 2);
    int colb = nt * 128 + wc * 64 + l15;
    if (RELU) {
        float b2c[4];
#pragma unroll
        for (int n = 0; n < 4; ++n) b2c[n] = biasv[colb + n * 16];
        float pm[4] = {0, 0, 0, 0}, ps2[4] = {0, 0, 0, 0}, pza[4] = {0, 0, 0, 0}, pah[4] = {0, 0, 0, 0};
#pragma unroll
        for (int m = 0; m < 4; ++m) {
#pragma unroll
            for (int q = 0; q < 4; ++q) {
                int row = rowb + m * 16 + q;
                bool ok = row < NT;
                int rowc = ok ? row : (NT - 1);
                float okf = ok ? 1.f : 0.f;
                float a = Aw[b * NT + rowc] * okf;
                const float* hrow = hsrc + ((size_t)b * NT + rowc) * ND;
#pragma unroll
                for (int n = 0; n < 4; ++n) {
                    float hv = hrow[colb + n * 16] * okf;
                    float o2 = acc[m][n][q] + b2c[n];
                    pm[n] = fmaf(o2, hv, pm[n]);
                    ps2[n] = fmaf(o2 * hv, hv, ps2[n]);
                    pza[n] = fmaf(a, o2, pza[n]);
                    pah[n] = fmaf(a, hv, pah[n]);
                }
            }
        }
#pragma unroll
        for (int n = 0; n < 4; ++n) {
            pm[n] += __shfl_xor(pm[n], 16); pm[n] += __shfl_xor(pm[n], 32);
            ps2[n] += __shfl_xor(ps2[n], 16); ps2[n] += __shfl_xor(ps2[n], 32);
            pza[n] += __shfl_xor(pza[n], 16); pza[n] += __shfl_xor(pza[n], 32);
            pah[n] += __shfl_xor(pah[n], 16); pah[n] += __shfl_xor(pah[n], 32);
            if (kg == 0) {
                int col = colb + n * 16;
                atomicAdd(&mup[b * ND + col], pm[n]);
                atomicAdd(&s2p[b * ND + col], ps2[n]);
                atomicAdd(&zab[b * ND + col], pza[n]);
                atomicAdd(&ahb[b * ND + col], pah[n]);
            }
        }
    } else {
#pragma unroll
        for (int m = 0; m < 4; ++m)
#pragma unroll
            for (int q = 0; q < 4; ++q) {
                int row = rowb + m * 16 + q;
                if (row < NT) {
                    float* orow = Out + ((size_t)b * NT + row) * NP;
#pragma unroll
                    for (int n = 0; n < 4; ++n)
                        orow[colb + n * 16] = acc[m][n][q] + biasv[b * NP + colb + n * 16];
                }
            }
    }
}

// ---------------- per-iteration small kernels ----------------
// grid (4, 32), block 256
__global__ void k_cvec(const float* __restrict__ C, const float* __restrict__ Wc,
                       float* __restrict__ cvec) {
    int p = blockIdx.x * 256 + threadIdx.x;
    int d0 = blockIdx.y * 48, d1 = d0 + 48;
    float acc[NB];
#pragma unroll
    for (int b = 0; b < NB; ++b) acc[b] = 0.f;
    for (int d = d0; d < d1; ++d) {
        float wc = Wc[(size_t)d * NP + p];
#pragma unroll
        for (int b = 0; b < NB; ++b) acc[b] += C[b * ND + d] * wc;
    }
#pragma unroll
    for (int b = 0; b < NB; ++b) atomicAdd(&cvec[b * NP + p], acc[b]);
}

__global__ void k_softmax(const float* __restrict__ att, const float* __restrict__ emask,
                          const float* __restrict__ b2m, float* __restrict__ A) {
    __shared__ float red[256];
    int b = blockIdx.x, tid = threadIdx.x;
    float bm = b2m[0];
    const float* x = att + (size_t)b * NT;
    const float* em = emask + (size_t)b * NT;
    float* a = A + (size_t)b * NT;
    float mx = -3.4e38f;
    for (int t = tid; t < NT; t += 256) {
        float v = (em[t] > 0.5f) ? x[t] + bm : NEGINF;
        mx = fmaxf(mx, v);
    }
    red[tid] = mx; __syncthreads();
    for (int s = 128; s > 0; s >>= 1) {
        if (tid < s) red[tid] = fmaxf(red[tid], red[tid + s]);
        __syncthreads();
    }
    mx = red[0]; __syncthreads();
    float sm = 0.f;
    for (int t = tid; t < NT; t += 256) {
        float v = (em[t] > 0.5f) ? x[t] + bm : NEGINF;
        float e = expf(v - mx); a[t] = e; sm += e;
    }
    float s1 = block_reduce_sum(sm, red);
    float inv1 = 1.f / s1;
    float sm2 = 0.f;
    for (int t = tid; t < NT; t += 256) { float v = a[t] * inv1; a[t] = v; sm2 += v; }
    float s2 = block_reduce_sum(sm2, red);
    float inv2 = 1.f / (s2 + 1e-8f);
    for (int t = tid; t < NT; t += 256) a[t] *= inv2;
}

// fused sigma + emb + embnorm + C-update + stop; grid NB, block 256
__global__ void k_tail(const float* __restrict__ red4, const float* __restrict__ w0,
                       const float* __restrict__ b0, const float* __restrict__ Wstop,
                       const float* __restrict__ bstop, const float* __restrict__ thr,
                       float* __restrict__ Cb, float* __restrict__ stopf,
                       float* __restrict__ Eout, float* __restrict__ Pout, int iter) {
    __shared__ float mus[ND], sgs[ND];
    __shared__ float red[256];
    int b = blockIdx.x, tid = threadIdx.x;
    const float* mup = red4 + (size_t)b * ND;
    const float* s2p = red4 + (size_t)NB * ND + b * ND;
    const float* Ahb = red4 + (size_t)2 * NB * ND + b * ND;
    const float* zAb = red4 + (size_t)3 * NB * ND + b * ND;
    for (int d = tid; d < ND; d += 256) {
        float mu = mup[d];
        mus[d] = mu;
        sgs[d] = sqrtf(fmaxf(s2p[d] - mu * mu, 1e-8f));
    }
    __syncthreads();
    float emb = 0.f;
    if (tid < NE) {
#pragma unroll 4
        for (int d = 0; d < ND; ++d)
            emb += mus[d] * w0[(size_t)d * NE + tid] + sgs[d] * w0[(size_t)(ND + d) * NE + tid];
        emb += b0[tid];
    }
    float nrm = block_reduce_sum((tid < NE) ? emb * emb : 0.f, red);
    float sc = 1.f / fmaxf(sqrtf(nrm), 1e-12f);
    if (tid < NE) Eout[((size_t)b * NITER + iter) * NE + tid] = emb * sc;
    float active = (stopf[b] > 0.5f) ? 0.f : 1.f;
    float dsum = 0.f;
    for (int d = tid; d < ND; d += 256) {
        float Cn = Cb[b * ND + d] + active * (Ahb[d] * (1.f / NT));
        Cb[b * ND + d] = Cn;
        dsum += zAb[d] * Wstop[d] + Cn * Wstop[ND + d];
    }
    float s = block_reduce_sum(dsum, red);
    if (tid == 0) {
        float logit = s + bstop[0];
        float p = 1.f / (1.f + expf(-logit));
        Pout[b * NITER + iter] = p;
        if (p < thr[0]) stopf[b] = 1.f;
    }
}

__global__ void k_mask(float* __restrict__ Eout, const float* __restrict__ Pout,
                       const float* __restrict__ thr) {
    __shared__ float run;
    int b = blockIdx.x, tid = threadIdx.x;
    if (tid == 0) run = 1.f;
    __syncthreads();
    for (int j = 0; j < NITER; ++j) {
        if (tid == 0) { if (Pout[b * NITER + j] < thr[0]) run = 0.f; }
        __syncthreads();
        Eout[((size_t)b * NITER + j) * NE + tid] *= run;
        __syncthreads();
    }
}

// ---------------- launch ----------------
extern "C" void kernel_launch(void* const* d_in, const int* in_sizes, int n_in,
                              void* d_out, int out_size, void* d_ws, size_t ws_size,
                              hipStream_t stream) {
    const float* h = (const float*)d_in[0];
    const float* W1 = (const float*)d_in[1];
    const float* Wc = (const float*)d_in[2];
    const float* W2 = (const float*)d_in[3];
    const float* b2 = (const float*)d_in[4];
    const float* w0 = (const float*)d_in[5];
    const float* b0 = (const float*)d_in[6];
    const float* Wstop = (const float*)d_in[7];
    const float* bstop = (const float*)d_in[8];
    const float* thr = (const float*)d_in[9];
    const float* C0 = (const float*)d_in[10];

    float* Eout = (float*)d_out;
    float* Pout = Eout + (size_t)NB * NITER * NE;

    char* wsb = (char*)d_ws;
    size_t off = 0;
    auto alloc = [&](size_t bytes) -> void* {
        void* p = wsb + off; off += (bytes + 15) & ~(size_t)15; return p;
    };

    float* base = (float*)alloc((size_t)NB * NT * NP * 4);
    unsigned short* rel_h = (unsigned short*)alloc((size_t)NB * 12 * 32 * 4096 * 2);
    unsigned short* w1t_h = (unsigned short*)alloc((size_t)8 * 48 * 4096 * 2);
    unsigned short* w1t_l = (unsigned short*)alloc((size_t)8 * 48 * 4096 * 2);
    unsigned short* w2t_h = (unsigned short*)alloc((size_t)12 * 32 * 4096 * 2);
    unsigned short* w2t_l = (unsigned short*)alloc((size_t)12 * 32 * 4096 * 2);
    float* mu0 = (float*)alloc((size_t)2 * NB * ND * 4);  // mu0 + sig0 contiguous
    float* sig0 = mu0 + NB * ND;
    float* emask = (float*)alloc(NB * NT * 4);
    float* biasb = (float*)alloc(NB * NP * 4);
    float* w2r = (float*)alloc(NP * 4);
    float* b2m = (float*)alloc(16);
    // zero-region: cvec | att | red4 (contiguous, one memset per iteration)
    float* cvec = (float*)alloc(((size_t)NB * NP + NB * NT + 4 * NB * ND) * 4);
    float* att = cvec + NB * NP;
    float* red4 = att + NB * NT;
    float* mup = red4;
    float* s2p = red4 + NB * ND;
    float* Ahb = red4 + 2 * NB * ND;
    float* zAb = red4 + 3 * NB * ND;
    float* Abuf = (float*)alloc(NB * NT * 4);
    float* Cb = (float*)alloc(NB * ND * 4);
    float* stopf = (float*)alloc(32);
    size_t zero_bytes = ((size_t)NB * NP + NB * NT + 4 * NB * ND) * 4;

    // ---- pre-pass ----
    hipMemsetAsync(mu0, 0, (size_t)2 * NB * ND * 4, stream);
    hipMemsetAsync(biasb, 0, (size_t)NB * NP * 4, stream);
    k_colstats<<<dim3(ND / 256, NB, 12), 256, 0, stream>>>(h, mu0, sig0);
    k_stats_fin<<<dim3(NB * ND / 256), 256, 0, stream>>>(mu0, sig0);
    k_energy<<<dim3(NT, NB), 256, 0, stream>>>(h, emask);
    k_w2r<<<dim3(NP + 1), 256, 0, stream>>>(W2, b2, w2r, b2m);
    k_biasb<<<dim3(NP / 256, 8), 256, 0, stream>>>(W1, mu0, sig0, biasb);
    k_split_w<<<dim3(8, 48), 256, 0, stream>>>(W1, NP, 48, w1t_h, w1t_l);
    k_split_w<<<dim3(12, 32), 256, 0, stream>>>(W2, ND, 32, w2t_h, w2t_l);
    k_gemm_mfma<false><<<dim3(12, 8, NB), 256, 0, stream>>>(
        h, nullptr, w1t_h, w1t_l, biasb, base, nullptr, nullptr, nullptr, nullptr, nullptr);
    k_init<<<dim3(ND / 256, NB), 256, 0, stream>>>(Cb, C0, stopf);

    // ---- iterations ----
    for (int i = 0; i < NITER; ++i) {
        hipMemsetAsync(cvec, 0, zero_bytes, stream);
        k_cvec<<<dim3(4, 32), 256, 0, stream>>>(Cb, Wc, cvec);
        k_relu_att<<<dim3(12, 32, NB), 256, 0, stream>>>(base, cvec, w2r, rel_h, att);
        k_softmax<<<dim3(NB), 256, 0, stream>>>(att, emask, b2m, Abuf);
        k_gemm_mfma<true><<<dim3(12, 12, NB), 256, 0, stream>>>(
            h, rel_h, w2t_h, w2t_l, b2, nullptr, Abuf, mup, s2p, zAb, Ahb);
        k_tail<<<dim3(NB), 256, 0, stream>>>(red4, w0, b0, Wstop, bstop, thr,
                                             Cb, stopf, Eout, Pout, i);
    }
    k_mask<<<dim3(NB), 192, 0, stream>>>(Eout, Pout, thr);
}

// Round 5
// 1301.885 us; speedup vs baseline: 2.2607x; 1.5174x over previous
//
#include <hip/hip_runtime.h>
#include <math.h>

#define NB 8
#define NT 1500
#define ND 1536
#define NP 1024
#define NE 192
#define NITER 6
#define NEGINF -1e30f

typedef __attribute__((ext_vector_type(8))) short bf16x8;
typedef __attribute__((ext_vector_type(4))) float f32x4;
typedef __attribute__((ext_vector_type(8))) unsigned short us16x8;

__device__ __forceinline__ unsigned short bf_rne(float x) {
    unsigned u = __float_as_uint(x);
    return (unsigned short)((u + 0x7FFFu + ((u >> 16) & 1u)) >> 16);
}
__device__ __forceinline__ float bf_f(unsigned short u) {
    return __uint_as_float(((unsigned)u) << 16);
}

// ---------------- helpers ----------------
__device__ __forceinline__ float block_reduce_sum(float v, float* red) {
    int tid = threadIdx.x;
    red[tid] = v; __syncthreads();
    for (int s = blockDim.x >> 1; s > 0; s >>= 1) {
        if (tid < s) red[tid] += red[tid + s];
        __syncthreads();
    }
    float r = red[0]; __syncthreads();
    return r;
}

// ---------------- pre-pass kernels ----------------
__global__ void k_colstats(const float* __restrict__ h, float* __restrict__ sum1,
                           float* __restrict__ sum2) {
    int d = blockIdx.x * 256 + threadIdx.x;
    int b = blockIdx.y;
    int t0 = blockIdx.z * 125, t1 = t0 + 125;
    const float* hp = h + (size_t)b * NT * ND + d;
    float s = 0.f, s2 = 0.f;
    for (int t = t0; t < t1; ++t) { float v = hp[(size_t)t * ND]; s += v; s2 += v * v; }
    atomicAdd(&sum1[b * ND + d], s);
    atomicAdd(&sum2[b * ND + d], s2);
}

__global__ void k_stats_fin(float* __restrict__ mu0, float* __restrict__ sig0) {
    int i = blockIdx.x * 256 + threadIdx.x;
    float mu = mu0[i] * (1.f / NT);
    float sec = sig0[i] * (1.f / NT);
    mu0[i] = mu;
    sig0[i] = sqrtf(fmaxf(sec - mu * mu, 1e-8f));
}

__global__ void k_energy(const float* __restrict__ h, float* __restrict__ emask) {
    __shared__ float red[256];
    int t = blockIdx.x, b = blockIdx.y;
    const float* hp = h + ((size_t)b * NT + t) * ND;
    float s = 0.f;
    for (int d = threadIdx.x; d < ND; d += 256) { float v = hp[d]; s += v * v; }
    s = block_reduce_sum(s, red);
    if (threadIdx.x == 0) emask[b * NT + t] = (s * (1.f / ND) > 1e-4f) ? 1.f : 0.f;
}

__global__ void k_w2r(const float* __restrict__ W2, const float* __restrict__ b2,
                      float* __restrict__ w2r, float* __restrict__ b2m) {
    __shared__ float red[256];
    int p = blockIdx.x;
    float s = 0.f;
    if (p < NP) {
        const float* row = W2 + (size_t)p * ND;
        for (int d = threadIdx.x; d < ND; d += 256) s += row[d];
        s = block_reduce_sum(s, red);
        if (threadIdx.x == 0) w2r[p] = s * (1.f / ND);
    } else {
        for (int d = threadIdx.x; d < ND; d += 256) s += b2[d];
        s = block_reduce_sum(s, red);
        if (threadIdx.x == 0) b2m[0] = s * (1.f / ND);
    }
}

__global__ void k_biasb(const float* __restrict__ W1, const float* __restrict__ mu0,
                        const float* __restrict__ sig0, float* __restrict__ biasb) {
    int p = blockIdx.x * 256 + threadIdx.x;
    int d0 = blockIdx.y * 192, d1 = d0 + 192;
    float acc[NB];
#pragma unroll
    for (int b = 0; b < NB; ++b) acc[b] = 0.f;
    for (int d = d0; d < d1; ++d) {
        float wa = W1[(size_t)(ND + d) * NP + p];
        float wb = W1[(size_t)(2 * ND + d) * NP + p];
#pragma unroll
        for (int b = 0; b < NB; ++b)
            acc[b] += mu0[b * ND + d] * wa + sig0[b * ND + d] * wb;
    }
#pragma unroll
    for (int b = 0; b < NB; ++b) atomicAdd(&biasb[b * NP + p], acc[b]);
}

__global__ void k_init(float* __restrict__ C, const float* __restrict__ C0,
                       float* __restrict__ stopf) {
    int d = blockIdx.x * 256 + threadIdx.x;
    int b = blockIdx.y;
    C[b * ND + d] = C0[d];
    if (blockIdx.x == 0 && threadIdx.x == 0) stopf[b] = 0.f;
}

// ---------------- weight split (once): W [K][N] f32 -> tiled swizzled bf16 hi/lo ----------------
__global__ void k_split_w(const float* __restrict__ W, int ldw, int kcnt,
                          unsigned short* __restrict__ th, unsigned short* __restrict__ tl) {
    __shared__ float t[128][33];
    int nt = blockIdx.x, kc = blockIdx.y, tid = threadIdx.x;
    int col = tid & 127, kh = tid >> 7;
    const float* wp = W + (size_t)(kc * 32 + kh) * ldw + nt * 128 + col;
#pragma unroll
    for (int i = 0; i < 16; ++i)
        t[col][kh + 2 * i] = wp[(size_t)(2 * i) * ldw];
    __syncthreads();
    int r = tid >> 1;
    int swz = (r >> 1) & 3;
    size_t tb = ((size_t)nt * kcnt + kc) * 4096;
#pragma unroll
    for (int j = 0; j < 2; ++j) {
        int so = (tid & 1) * 2 + j;
        int s = so ^ swz;
        us16x8 hv, lv;
#pragma unroll
        for (int q = 0; q < 8; ++q) {
            float x = t[r][s * 8 + q];
            unsigned short hh = bf_rne(x);
            hv[q] = hh;
            lv[q] = bf_rne(x - bf_f(hh));
        }
        *(us16x8*)&th[tb + r * 32 + so * 8] = hv;
        *(us16x8*)&tl[tb + r * 32 + so * 8] = lv;
    }
}

// ---------------- per-iter fused: relu(base+cvec) -> hi tile, + att partial sums ----------------
// grid (12, 32, NB), block 256
__global__ void k_relu_att(const float* __restrict__ base, const float* __restrict__ cvec,
                           const float* __restrict__ w2r, unsigned short* __restrict__ th,
                           float* __restrict__ att) {
    int tr = blockIdx.x, kc = blockIdx.y, b = blockIdx.z;
    int tid = threadIdx.x;
    int r = tid >> 1, quad = tid & 1;
    int row = tr * 128 + r;
    bool ok = row < NT;
    size_t tb = ((size_t)(b * 12 + tr) * 32 + kc) * 4096;
    const float* bp = base + ((size_t)b * NT + row) * NP + kc * 32 + quad * 16;
    const float* cv = cvec + b * NP + kc * 32 + quad * 16;
    const float* wr = w2r + kc * 32 + quad * 16;
    int swz = (r >> 1) & 3;
    float asum = 0.f;
#pragma unroll
    for (int half = 0; half < 2; ++half) {
        us16x8 hv;
#pragma unroll
        for (int j = 0; j < 2; ++j) {
            float x0 = 0.f, x1 = 0.f, x2 = 0.f, x3 = 0.f;
            if (ok) {
                float4 v = *(const float4*)(bp + half * 8 + j * 4);
                float4 c4 = *(const float4*)(cv + half * 8 + j * 4);
                float4 w4 = *(const float4*)(wr + half * 8 + j * 4);
                x0 = fmaxf(v.x + c4.x, 0.f); x1 = fmaxf(v.y + c4.y, 0.f);
                x2 = fmaxf(v.z + c4.z, 0.f); x3 = fmaxf(v.w + c4.w, 0.f);
                asum += x0 * w4.x + x1 * w4.y + x2 * w4.z + x3 * w4.w;
            }
            hv[j * 4 + 0] = bf_rne(x0); hv[j * 4 + 1] = bf_rne(x1);
            hv[j * 4 + 2] = bf_rne(x2); hv[j * 4 + 3] = bf_rne(x3);
        }
        int off = r * 32 + (((quad * 2 + half) ^ swz) << 3);
        *(us16x8*)&th[tb + off] = hv;
    }
    asum += __shfl_xor(asum, 1);
    if (ok && quad == 0) atomicAdd(&att[b * NT + row], asum);
}

// ---------------- MFMA GEMM, single-buffered ----------------
// RELU=true : A = pre-split relu hi tiles, 2-term (ah*bh + ah*bl), K=1024, N=1536;
//             epilogue accumulates mu_p/s2p/zA/Ah
// RELU=false: A = h (f32, on-the-fly hi/lo split), 3-term, K=1536, N=1024;
//             epilogue writes base(+biasb)
template <bool RELU>
__global__ __launch_bounds__(256, 4) void k_gemm_mfma(
    const float* __restrict__ hsrc, const unsigned short* __restrict__ at_h,
    const unsigned short* __restrict__ bt_h, const unsigned short* __restrict__ bt_l,
    const float* __restrict__ biasv, float* __restrict__ Out,
    const float* __restrict__ Aw, float* __restrict__ mup, float* __restrict__ s2p,
    float* __restrict__ zab, float* __restrict__ ahb) {
    constexpr int K = RELU ? NP : ND;
    constexpr int KC = K / 32;
    __shared__ unsigned short As_h[4096];
    __shared__ unsigned short As_l[RELU ? 16 : 4096];
    __shared__ unsigned short Bs_h[4096];
    __shared__ unsigned short Bs_l[4096];
    int b = blockIdx.z, tr = blockIdx.x, nt = blockIdx.y;
    int tid = threadIdx.x;
    int lane = tid & 63, w = tid >> 6;
    int wr = w >> 1, wc = w & 1;
    int l15 = lane & 15, kg = lane >> 4;
    int sw = (l15 >> 1) & 3;
    f32x4 acc[4][4];
#pragma unroll
    for (int m = 0; m < 4; ++m)
#pragma unroll
        for (int n = 0; n < 4; ++n) acc[m][n] = (f32x4){0.f, 0.f, 0.f, 0.f};
    int aoff[4], boff[4];
#pragma unroll
    for (int m = 0; m < 4; ++m) aoff[m] = (wr * 64 + m * 16 + l15) * 32 + ((kg ^ sw) << 3);
#pragma unroll
    for (int n = 0; n < 4; ++n) boff[n] = (wc * 64 + n * 16 + l15) * 32 + ((kg ^ sw) << 3);

    const unsigned short* gbh = bt_h + ((size_t)nt * KC) * 4096 + lane * 8;
    const unsigned short* gbl = bt_l + ((size_t)nt * KC) * 4096 + lane * 8;
    const unsigned short* ga = RELU ? (at_h + ((size_t)(b * 12 + tr) * KC) * 4096 + lane * 8)
                                    : nullptr;

    // on-the-fly A (base path)
    int r2 = tid >> 1, quad = tid & 1;
    int arow = tr * 128 + r2;
    bool aok = arow < NT;
    int aswz = (r2 >> 1) & 3;
    const float* hp = hsrc + ((size_t)b * NT + arow) * ND + quad * 16;

    for (int kc = 0; kc < KC; ++kc) {
        if (RELU) {
            // 24 segments: As_h(8) Bs_h(8) Bs_l(8); 6 per wave
#pragma unroll
            for (int c = 0; c < 6; ++c) {
                int seg = w * 6 + c;
                int bufid = seg >> 3, part = seg & 7;
                const unsigned short* src =
                    (bufid == 0 ? ga : bufid == 1 ? gbh : gbl) + (size_t)kc * 4096 + part * 512;
                unsigned short* dst =
                    (bufid == 0 ? &As_h[0] : bufid == 1 ? &Bs_h[0] : &Bs_l[0]) + part * 512;
                __builtin_amdgcn_global_load_lds(src, dst, 16, 0, 0);
            }
        } else {
            // 16 segments: Bs_h(8) Bs_l(8); 4 per wave
#pragma unroll
            for (int c = 0; c < 4; ++c) {
                int seg = w * 4 + c;
                int part = seg & 7;
                const unsigned short* src =
                    ((seg >> 3) == 0 ? gbh : gbl) + (size_t)kc * 4096 + part * 512;
                unsigned short* dst = ((seg >> 3) == 0 ? &Bs_h[0] : &Bs_l[0]) + part * 512;
                __builtin_amdgcn_global_load_lds(src, dst, 16, 0, 0);
            }
            // A: f32 load, split to hi/lo, LDS write
#pragma unroll
            for (int i = 0; i < 4; ++i) {
                int kk = quad * 16 + i * 4;
                float x0 = 0.f, x1 = 0.f, x2 = 0.f, x3 = 0.f;
                if (aok) {
                    float4 v = *(const float4*)(hp + kc * 32 + i * 4);
                    x0 = v.x; x1 = v.y; x2 = v.z; x3 = v.w;
                }
                unsigned short h0 = bf_rne(x0), h1 = bf_rne(x1), h2 = bf_rne(x2), h3 = bf_rne(x3);
                int off = r2 * 32 + (((kk >> 3) ^ aswz) << 3) + (kk & 7);
                *(ushort4*)&As_h[off] = make_ushort4(h0, h1, h2, h3);
                *(ushort4*)&As_l[off] = make_ushort4(bf_rne(x0 - bf_f(h0)), bf_rne(x1 - bf_f(h1)),
                                                     bf_rne(x2 - bf_f(h2)), bf_rne(x3 - bf_f(h3)));
            }
        }
        __syncthreads();
        bf16x8 ahf[4], alf[4];
#pragma unroll
        for (int m = 0; m < 4; ++m) {
            ahf[m] = *(const bf16x8*)&As_h[aoff[m]];
            if (!RELU) alf[m] = *(const bf16x8*)&As_l[aoff[m]];
        }
#pragma unroll
        for (int n = 0; n < 4; ++n) {
            bf16x8 bh = *(const bf16x8*)&Bs_h[boff[n]];
            bf16x8 bl = *(const bf16x8*)&Bs_l[boff[n]];
#pragma unroll
            for (int m = 0; m < 4; ++m) {
                acc[m][n] = __builtin_amdgcn_mfma_f32_16x16x32_bf16(ahf[m], bh, acc[m][n], 0, 0, 0);
                acc[m][n] = __builtin_amdgcn_mfma_f32_16x16x32_bf16(ahf[m], bl, acc[m][n], 0, 0, 0);
                if (!RELU)
                    acc[m][n] = __builtin_amdgcn_mfma_f32_16x16x32_bf16(alf[m], bh, acc[m][n], 0, 0, 0);
            }
        }
        __syncthreads();
    }

    int rowb = tr * 128 + wr * 64 + (kg << 2);
    int colb = nt * 128 + wc * 64 + l15;
    if (RELU) {
        float b2c[4];
#pragma unroll
        for (int n = 0; n < 4; ++n) b2c[n] = biasv[colb + n * 16];
        float pm[4] = {0, 0, 0, 0}, ps2[4] = {0, 0, 0, 0}, pza[4] = {0, 0, 0, 0}, pah[4] = {0, 0, 0, 0};
#pragma unroll
        for (int m = 0; m < 4; ++m) {
#pragma unroll
            for (int q = 0; q < 4; ++q) {
                int row = rowb + m * 16 + q;
                bool ok = row < NT;
                int rowc = ok ? row : (NT - 1);
                float okf = ok ? 1.f : 0.f;
                float a = Aw[b * NT + rowc] * okf;
                const float* hrow = hsrc + ((size_t)b * NT + rowc) * ND;
#pragma unroll
                for (int n = 0; n < 4; ++n) {
                    float hv = hrow[colb + n * 16] * okf;
                    float o2 = acc[m][n][q] + b2c[n];
                    pm[n] = fmaf(o2, hv, pm[n]);
                    ps2[n] = fmaf(o2 * hv, hv, ps2[n]);
                    pza[n] = fmaf(a, o2, pza[n]);
                    pah[n] = fmaf(a, hv, pah[n]);
                }
            }
        }
#pragma unroll
        for (int n = 0; n < 4; ++n) {
            pm[n] += __shfl_xor(pm[n], 16); pm[n] += __shfl_xor(pm[n], 32);
            ps2[n] += __shfl_xor(ps2[n], 16); ps2[n] += __shfl_xor(ps2[n], 32);
            pza[n] += __shfl_xor(pza[n], 16); pza[n] += __shfl_xor(pza[n], 32);
            pah[n] += __shfl_xor(pah[n], 16); pah[n] += __shfl_xor(pah[n], 32);
            if (kg == 0) {
                int col = colb + n * 16;
                atomicAdd(&mup[b * ND + col], pm[n]);
                atomicAdd(&s2p[b * ND + col], ps2[n]);
                atomicAdd(&zab[b * ND + col], pza[n]);
                atomicAdd(&ahb[b * ND + col], pah[n]);
            }
        }
    } else {
#pragma unroll
        for (int m = 0; m < 4; ++m)
#pragma unroll
            for (int q = 0; q < 4; ++q) {
                int row = rowb + m * 16 + q;
                if (row < NT) {
                    float* orow = Out + ((size_t)b * NT + row) * NP;
#pragma unroll
                    for (int n = 0; n < 4; ++n)
                        orow[colb + n * 16] = acc[m][n][q] + biasv[b * NP + colb + n * 16];
                }
            }
    }
}

// ---------------- per-iteration small kernels ----------------
// grid (4, 32), block 256
__global__ void k_cvec(const float* __restrict__ C, const float* __restrict__ Wc,
                       float* __restrict__ cvec) {
    int p = blockIdx.x * 256 + threadIdx.x;
    int d0 = blockIdx.y * 48, d1 = d0 + 48;
    float acc[NB];
#pragma unroll
    for (int b = 0; b < NB; ++b) acc[b] = 0.f;
    for (int d = d0; d < d1; ++d) {
        float wc = Wc[(size_t)d * NP + p];
#pragma unroll
        for (int b = 0; b < NB; ++b) acc[b] += C[b * ND + d] * wc;
    }
#pragma unroll
    for (int b = 0; b < NB; ++b) atomicAdd(&cvec[b * NP + p], acc[b]);
}

__global__ void k_softmax(const float* __restrict__ att, const float* __restrict__ emask,
                          const float* __restrict__ b2m, float* __restrict__ A) {
    __shared__ float red[256];
    int b = blockIdx.x, tid = threadIdx.x;
    float bm = b2m[0];
    const float* x = att + (size_t)b * NT;
    const float* em = emask + (size_t)b * NT;
    float* a = A + (size_t)b * NT;
    float mx = -3.4e38f;
    for (int t = tid; t < NT; t += 256) {
        float v = (em[t] > 0.5f) ? x[t] + bm : NEGINF;
        mx = fmaxf(mx, v);
    }
    red[tid] = mx; __syncthreads();
    for (int s = 128; s > 0; s >>= 1) {
        if (tid < s) red[tid] = fmaxf(red[tid], red[tid + s]);
        __syncthreads();
    }
    mx = red[0]; __syncthreads();
    float sm = 0.f;
    for (int t = tid; t < NT; t += 256) {
        float v = (em[t] > 0.5f) ? x[t] + bm : NEGINF;
        float e = expf(v - mx); a[t] = e; sm += e;
    }
    float s1 = block_reduce_sum(sm, red);
    float inv1 = 1.f / s1;
    float sm2 = 0.f;
    for (int t = tid; t < NT; t += 256) { float v = a[t] * inv1; a[t] = v; sm2 += v; }
    float s2 = block_reduce_sum(sm2, red);
    float inv2 = 1.f / (s2 + 1e-8f);
    for (int t = tid; t < NT; t += 256) a[t] *= inv2;
}

// parallel emb accumulation: grid 32, block 192
// block bx handles d in [bx*48, bx*48+48); sigma computed in-block from mup/s2p
__global__ void k_embacc(const float* __restrict__ red4, const float* __restrict__ w0,
                         float* __restrict__ embt) {
    __shared__ float mus[NB][48], sgs[NB][48];
    int e = threadIdx.x;
    int d0 = blockIdx.x * 48;
    const float* mup = red4;
    const float* s2p = red4 + (size_t)NB * ND;
    for (int idx = e; idx < NB * 48; idx += 192) {
        int b = idx / 48, dd = idx % 48;
        float mu = mup[b * ND + d0 + dd];
        mus[b][dd] = mu;
        sgs[b][dd] = sqrtf(fmaxf(s2p[b * ND + d0 + dd] - mu * mu, 1e-8f));
    }
    __syncthreads();
    float acc[NB];
#pragma unroll
    for (int b = 0; b < NB; ++b) acc[b] = 0.f;
    for (int dd = 0; dd < 48; ++dd) {
        float wa = w0[(size_t)(d0 + dd) * NE + e];
        float wb = w0[(size_t)(ND + d0 + dd) * NE + e];
#pragma unroll
        for (int b = 0; b < NB; ++b)
            acc[b] += mus[b][dd] * wa + sgs[b][dd] * wb;
    }
#pragma unroll
    for (int b = 0; b < NB; ++b) atomicAdd(&embt[b * NE + e], acc[b]);
}

// C-update + stop prob + masked emb-norm write; grid NB, block 256
__global__ void k_tail2(const float* __restrict__ red4, const float* __restrict__ embt,
                        const float* __restrict__ b0, const float* __restrict__ Wstop,
                        const float* __restrict__ bstop, const float* __restrict__ thr,
                        float* __restrict__ Cb, float* __restrict__ stopf,
                        float* __restrict__ Eout, float* __restrict__ Pout, int iter) {
    __shared__ float red[256];
    __shared__ float liveflag;
    int b = blockIdx.x, tid = threadIdx.x;
    const float* Ahb = red4 + (size_t)2 * NB * ND + b * ND;
    const float* zAb = red4 + (size_t)3 * NB * ND + b * ND;
    float active = (stopf[b] > 0.5f) ? 0.f : 1.f;
    float dsum = 0.f;
    for (int d = tid; d < ND; d += 256) {
        float Cn = Cb[b * ND + d] + active * (Ahb[d] * (1.f / NT));
        Cb[b * ND + d] = Cn;
        dsum += zAb[d] * Wstop[d] + Cn * Wstop[ND + d];
    }
    float s = block_reduce_sum(dsum, red);
    if (tid == 0) {
        float logit = s + bstop[0];
        float p = 1.f / (1.f + expf(-logit));
        Pout[b * NITER + iter] = p;
        bool newly = p < thr[0];
        if (newly) stopf[b] = 1.f;
        liveflag = (active > 0.5f && !newly) ? 1.f : 0.f;
    }
    __syncthreads();
    float live = liveflag;
    float emb = (tid < NE) ? (embt[b * NE + tid] + b0[tid]) : 0.f;
    float nrm = block_reduce_sum(emb * emb, red);
    float sc = live / fmaxf(sqrtf(nrm), 1e-12f);
    if (tid < NE) Eout[((size_t)b * NITER + iter) * NE + tid] = emb * sc;
}

// ---------------- launch ----------------
extern "C" void kernel_launch(void* const* d_in, const int* in_sizes, int n_in,
                              void* d_out, int out_size, void* d_ws, size_t ws_size,
                              hipStream_t stream) {
    const float* h = (const float*)d_in[0];
    const float* W1 = (const float*)d_in[1];
    const float* Wc = (const float*)d_in[2];
    const float* W2 = (const float*)d_in[3];
    const float* b2 = (const float*)d_in[4];
    const float* w0 = (const float*)d_in[5];
    const float* b0 = (const float*)d_in[6];
    const float* Wstop = (const float*)d_in[7];
    const float* bstop = (const float*)d_in[8];
    const float* thr = (const float*)d_in[9];
    const float* C0 = (const float*)d_in[10];

    float* Eout = (float*)d_out;
    float* Pout = Eout + (size_t)NB * NITER * NE;

    char* wsb = (char*)d_ws;
    size_t off = 0;
    auto alloc = [&](size_t bytes) -> void* {
        void* p = wsb + off; off += (bytes + 15) & ~(size_t)15; return p;
    };

    float* base = (float*)alloc((size_t)NB * NT * NP * 4);
    unsigned short* rel_h = (unsigned short*)alloc((size_t)NB * 12 * 32 * 4096 * 2);
    unsigned short* w1t_h = (unsigned short*)alloc((size_t)8 * 48 * 4096 * 2);
    unsigned short* w1t_l = (unsigned short*)alloc((size_t)8 * 48 * 4096 * 2);
    unsigned short* w2t_h = (unsigned short*)alloc((size_t)12 * 32 * 4096 * 2);
    unsigned short* w2t_l = (unsigned short*)alloc((size_t)12 * 32 * 4096 * 2);
    float* mu0 = (float*)alloc((size_t)2 * NB * ND * 4);  // mu0 + sig0 contiguous
    float* sig0 = mu0 + NB * ND;
    float* emask = (float*)alloc(NB * NT * 4);
    float* biasb = (float*)alloc(NB * NP * 4);
    float* w2r = (float*)alloc(NP * 4);
    float* b2m = (float*)alloc(16);
    // zero-region: cvec | att | red4 | embt (contiguous, one memset per iteration)
    size_t zelems = (size_t)NB * NP + NB * NT + 4 * NB * ND + NB * NE;
    float* cvec = (float*)alloc(zelems * 4);
    float* att = cvec + NB * NP;
    float* red4 = att + NB * NT;
    float* mup = red4;
    float* s2p = red4 + NB * ND;
    float* zAb = red4 + 3 * NB * ND;
    float* Ahb = red4 + 2 * NB * ND;
    float* embt = red4 + 4 * NB * ND;
    float* Abuf = (float*)alloc(NB * NT * 4);
    float* Cb = (float*)alloc(NB * ND * 4);
    float* stopf = (float*)alloc(32);
    size_t zero_bytes = zelems * 4;

    // ---- pre-pass ----
    hipMemsetAsync(mu0, 0, (size_t)2 * NB * ND * 4, stream);
    hipMemsetAsync(biasb, 0, (size_t)NB * NP * 4, stream);
    k_colstats<<<dim3(ND / 256, NB, 12), 256, 0, stream>>>(h, mu0, sig0);
    k_stats_fin<<<dim3(NB * ND / 256), 256, 0, stream>>>(mu0, sig0);
    k_energy<<<dim3(NT, NB), 256, 0, stream>>>(h, emask);
    k_w2r<<<dim3(NP + 1), 256, 0, stream>>>(W2, b2, w2r, b2m);
    k_biasb<<<dim3(NP / 256, 8), 256, 0, stream>>>(W1, mu0, sig0, biasb);
    k_split_w<<<dim3(8, 48), 256, 0, stream>>>(W1, NP, 48, w1t_h, w1t_l);
    k_split_w<<<dim3(12, 32), 256, 0, stream>>>(W2, ND, 32, w2t_h, w2t_l);
    k_gemm_mfma<false><<<dim3(12, 8, NB), 256, 0, stream>>>(
        h, nullptr, w1t_h, w1t_l, biasb, base, nullptr, nullptr, nullptr, nullptr, nullptr);
    k_init<<<dim3(ND / 256, NB), 256, 0, stream>>>(Cb, C0, stopf);

    // ---- iterations ----
    for (int i = 0; i < NITER; ++i) {
        hipMemsetAsync(cvec, 0, zero_bytes, stream);
        k_cvec<<<dim3(4, 32), 256, 0, stream>>>(Cb, Wc, cvec);
        k_relu_att<<<dim3(12, 32, NB), 256, 0, stream>>>(base, cvec, w2r, rel_h, att);
        k_softmax<<<dim3(NB), 256, 0, stream>>>(att, emask, b2m, Abuf);
        k_gemm_mfma<true><<<dim3(12, 12, NB), 256, 0, stream>>>(
            h, rel_h, w2t_h, w2t_l, b2, nullptr, Abuf, mup, s2p, zAb, Ahb);
        k_embacc<<<dim3(32), 192, 0, stream>>>(red4, w0, embt);
        k_tail2<<<dim3(NB), 256, 0, stream>>>(red4, embt, b0, Wstop, bstop, thr,
                                              Cb, stopf, Eout, Pout, i);
    }
}

// Round 6
// 1085.778 us; speedup vs baseline: 2.7106x; 1.1990x over previous
//
#include <hip/hip_runtime.h>
#include <math.h>

#define NB 8
#define NT 1500
#define ND 1536
#define NP 1024
#define NE 192
#define NITER 6
#define NEGINF -1e30f

typedef __attribute__((ext_vector_type(8))) short bf16x8;
typedef __attribute__((ext_vector_type(4))) float f32x4;
typedef __attribute__((ext_vector_type(8))) unsigned short us16x8;

__device__ __forceinline__ unsigned short bf_rne(float x) {
    unsigned u = __float_as_uint(x);
    return (unsigned short)((u + 0x7FFFu + ((u >> 16) & 1u)) >> 16);
}
__device__ __forceinline__ float bf_f(unsigned short u) {
    return __uint_as_float(((unsigned)u) << 16);
}

// ---------------- helpers ----------------
__device__ __forceinline__ float block_reduce_sum(float v, float* red) {
    int tid = threadIdx.x;
    red[tid] = v; __syncthreads();
    for (int s = blockDim.x >> 1; s > 0; s >>= 1) {
        if (tid < s) red[tid] += red[tid + s];
        __syncthreads();
    }
    float r = red[0]; __syncthreads();
    return r;
}

// ---------------- pre-pass kernels ----------------
__global__ void k_colstats(const float* __restrict__ h, float* __restrict__ sum1,
                           float* __restrict__ sum2) {
    int d = blockIdx.x * 256 + threadIdx.x;
    int b = blockIdx.y;
    int t0 = blockIdx.z * 125, t1 = t0 + 125;
    const float* hp = h + (size_t)b * NT * ND + d;
    float s = 0.f, s2 = 0.f;
    for (int t = t0; t < t1; ++t) { float v = hp[(size_t)t * ND]; s += v; s2 += v * v; }
    atomicAdd(&sum1[b * ND + d], s);
    atomicAdd(&sum2[b * ND + d], s2);
}

__global__ void k_stats_fin(float* __restrict__ mu0, float* __restrict__ sig0) {
    int i = blockIdx.x * 256 + threadIdx.x;
    float mu = mu0[i] * (1.f / NT);
    float sec = sig0[i] * (1.f / NT);
    mu0[i] = mu;
    sig0[i] = sqrtf(fmaxf(sec - mu * mu, 1e-8f));
}

__global__ void k_energy(const float* __restrict__ h, float* __restrict__ emask) {
    __shared__ float red[256];
    int t = blockIdx.x, b = blockIdx.y;
    const float* hp = h + ((size_t)b * NT + t) * ND;
    float s = 0.f;
    for (int d = threadIdx.x; d < ND; d += 256) { float v = hp[d]; s += v * v; }
    s = block_reduce_sum(s, red);
    if (threadIdx.x == 0) emask[b * NT + t] = (s * (1.f / ND) > 1e-4f) ? 1.f : 0.f;
}

__global__ void k_w2r(const float* __restrict__ W2, const float* __restrict__ b2,
                      float* __restrict__ w2r, float* __restrict__ b2m) {
    __shared__ float red[256];
    int p = blockIdx.x;
    float s = 0.f;
    if (p < NP) {
        const float* row = W2 + (size_t)p * ND;
        for (int d = threadIdx.x; d < ND; d += 256) s += row[d];
        s = block_reduce_sum(s, red);
        if (threadIdx.x == 0) w2r[p] = s * (1.f / ND);
    } else {
        for (int d = threadIdx.x; d < ND; d += 256) s += b2[d];
        s = block_reduce_sum(s, red);
        if (threadIdx.x == 0) b2m[0] = s * (1.f / ND);
    }
}

__global__ void k_biasb(const float* __restrict__ W1, const float* __restrict__ mu0,
                        const float* __restrict__ sig0, float* __restrict__ biasb) {
    int p = blockIdx.x * 256 + threadIdx.x;
    int d0 = blockIdx.y * 192, d1 = d0 + 192;
    float acc[NB];
#pragma unroll
    for (int b = 0; b < NB; ++b) acc[b] = 0.f;
    for (int d = d0; d < d1; ++d) {
        float wa = W1[(size_t)(ND + d) * NP + p];
        float wb = W1[(size_t)(2 * ND + d) * NP + p];
#pragma unroll
        for (int b = 0; b < NB; ++b)
            acc[b] += mu0[b * ND + d] * wa + sig0[b * ND + d] * wb;
    }
#pragma unroll
    for (int b = 0; b < NB; ++b) atomicAdd(&biasb[b * NP + p], acc[b]);
}

__global__ void k_init(float* __restrict__ C, const float* __restrict__ C0,
                       float* __restrict__ stopf) {
    int d = blockIdx.x * 256 + threadIdx.x;
    int b = blockIdx.y;
    C[b * ND + d] = C0[d];
    if (blockIdx.x == 0 && threadIdx.x == 0) stopf[b] = 0.f;
}

// ---------------- weight split (once): W [K][N] f32 -> tiled swizzled bf16 hi/lo ----------------
__global__ void k_split_w(const float* __restrict__ W, int ldw, int kcnt,
                          unsigned short* __restrict__ th, unsigned short* __restrict__ tl) {
    __shared__ float t[128][33];
    int nt = blockIdx.x, kc = blockIdx.y, tid = threadIdx.x;
    int col = tid & 127, kh = tid >> 7;
    const float* wp = W + (size_t)(kc * 32 + kh) * ldw + nt * 128 + col;
#pragma unroll
    for (int i = 0; i < 16; ++i)
        t[col][kh + 2 * i] = wp[(size_t)(2 * i) * ldw];
    __syncthreads();
    int r = tid >> 1;
    int swz = (r >> 1) & 3;
    size_t tb = ((size_t)nt * kcnt + kc) * 4096;
#pragma unroll
    for (int j = 0; j < 2; ++j) {
        int so = (tid & 1) * 2 + j;
        int s = so ^ swz;
        us16x8 hv, lv;
#pragma unroll
        for (int q = 0; q < 8; ++q) {
            float x = t[r][s * 8 + q];
            unsigned short hh = bf_rne(x);
            hv[q] = hh;
            lv[q] = bf_rne(x - bf_f(hh));
        }
        *(us16x8*)&th[tb + r * 32 + so * 8] = hv;
        *(us16x8*)&tl[tb + r * 32 + so * 8] = lv;
    }
}

// ---------------- per-iter fused: relu(base+cvec) -> hi tile, + att partial sums ----------------
// grid (12, 32, NB), block 256
__global__ void k_relu_att(const float* __restrict__ base, const float* __restrict__ cvec,
                           const float* __restrict__ w2r, unsigned short* __restrict__ th,
                           float* __restrict__ att) {
    int tr = blockIdx.x, kc = blockIdx.y, b = blockIdx.z;
    int tid = threadIdx.x;
    int r = tid >> 1, quad = tid & 1;
    int row = tr * 128 + r;
    bool ok = row < NT;
    size_t tb = ((size_t)(b * 12 + tr) * 32 + kc) * 4096;
    const float* bp = base + ((size_t)b * NT + row) * NP + kc * 32 + quad * 16;
    const float* cv = cvec + b * NP + kc * 32 + quad * 16;
    const float* wr = w2r + kc * 32 + quad * 16;
    int swz = (r >> 1) & 3;
    float asum = 0.f;
#pragma unroll
    for (int half = 0; half < 2; ++half) {
        us16x8 hv;
#pragma unroll
        for (int j = 0; j < 2; ++j) {
            float x0 = 0.f, x1 = 0.f, x2 = 0.f, x3 = 0.f;
            if (ok) {
                float4 v = *(const float4*)(bp + half * 8 + j * 4);
                float4 c4 = *(const float4*)(cv + half * 8 + j * 4);
                float4 w4 = *(const float4*)(wr + half * 8 + j * 4);
                x0 = fmaxf(v.x + c4.x, 0.f); x1 = fmaxf(v.y + c4.y, 0.f);
                x2 = fmaxf(v.z + c4.z, 0.f); x3 = fmaxf(v.w + c4.w, 0.f);
                asum += x0 * w4.x + x1 * w4.y + x2 * w4.z + x3 * w4.w;
            }
            hv[j * 4 + 0] = bf_rne(x0); hv[j * 4 + 1] = bf_rne(x1);
            hv[j * 4 + 2] = bf_rne(x2); hv[j * 4 + 3] = bf_rne(x3);
        }
        int off = r * 32 + (((quad * 2 + half) ^ swz) << 3);
        *(us16x8*)&th[tb + off] = hv;
    }
    asum += __shfl_xor(asum, 1);
    if (ok && quad == 0) atomicAdd(&att[b * NT + row], asum);
}

// ---------------- RELU GEMM: 1-term bf16, 2-phase double-buffered, XCD-swizzled ----------------
// A = pre-split relu hi tiles [b*12+tr][kc][128r][32k swz], B = W2 hi tiles, K=1024, N=1536
// epilogue accumulates mu_p/s2p/zA/Ah
__global__ __launch_bounds__(256, 4) void k_gemm_relu(
    const float* __restrict__ hsrc, const unsigned short* __restrict__ at_h,
    const unsigned short* __restrict__ bt_h, const float* __restrict__ b2,
    const float* __restrict__ Aw, float* __restrict__ mup, float* __restrict__ s2p,
    float* __restrict__ zab, float* __restrict__ ahb) {
    constexpr int KC = NP / 32;  // 32
    __shared__ unsigned short As[2][4096];
    __shared__ unsigned short Bs[2][4096];
    // XCD swizzle: grid 12x12x8 = 1152, chunk 144 = one b-plane per XCD
    int flat = blockIdx.x + 12 * (blockIdx.y + 12 * blockIdx.z);
    int swzf = (flat & 7) * 144 + (flat >> 3);
    int tr = swzf % 12, nt = (swzf / 12) % 12, b = swzf / 144;
    int tid = threadIdx.x;
    int lane = tid & 63, w = tid >> 6;
    int wr = w >> 1, wc = w & 1;
    int l15 = lane & 15, kg = lane >> 4;
    int sw = (l15 >> 1) & 3;
    f32x4 acc[4][4];
#pragma unroll
    for (int m = 0; m < 4; ++m)
#pragma unroll
        for (int n = 0; n < 4; ++n) acc[m][n] = (f32x4){0.f, 0.f, 0.f, 0.f};
    int aoff[4], boff[4];
#pragma unroll
    for (int m = 0; m < 4; ++m) aoff[m] = (wr * 64 + m * 16 + l15) * 32 + ((kg ^ sw) << 3);
#pragma unroll
    for (int n = 0; n < 4; ++n) boff[n] = (wc * 64 + n * 16 + l15) * 32 + ((kg ^ sw) << 3);

    const unsigned short* ga = at_h + ((size_t)(b * 12 + tr) * KC) * 4096 + lane * 8;
    const unsigned short* gb = bt_h + ((size_t)nt * KC) * 4096 + lane * 8;

    auto stage = [&](int buf, int kc) {
        // 16 segments: As(8) Bs(8); 4 per wave
#pragma unroll
        for (int c = 0; c < 4; ++c) {
            int seg = w * 4 + c;
            int part = seg & 7;
            const unsigned short* src = ((seg >> 3) == 0 ? ga : gb) + (size_t)kc * 4096 + part * 512;
            unsigned short* dst = ((seg >> 3) == 0 ? &As[buf][0] : &Bs[buf][0]) + part * 512;
            __builtin_amdgcn_global_load_lds(src, dst, 16, 0, 0);
        }
    };

    stage(0, 0);
    __syncthreads();
    int cur = 0;
    for (int kc = 0; kc < KC; ++kc) {
        if (kc + 1 < KC) stage(cur ^ 1, kc + 1);
        bf16x8 af[4], bf[4];
#pragma unroll
        for (int m = 0; m < 4; ++m) af[m] = *(const bf16x8*)&As[cur][aoff[m]];
#pragma unroll
        for (int n = 0; n < 4; ++n) bf[n] = *(const bf16x8*)&Bs[cur][boff[n]];
#pragma unroll
        for (int n = 0; n < 4; ++n)
#pragma unroll
            for (int m = 0; m < 4; ++m)
                acc[m][n] = __builtin_amdgcn_mfma_f32_16x16x32_bf16(af[m], bf[n], acc[m][n], 0, 0, 0);
        __syncthreads();
        cur ^= 1;
    }

    int rowb = tr * 128 + wr * 64 + (kg << 2);
    int colb = nt * 128 + wc * 64 + l15;
    float b2c[4];
#pragma unroll
    for (int n = 0; n < 4; ++n) b2c[n] = b2[colb + n * 16];
    float pm[4] = {0, 0, 0, 0}, ps2[4] = {0, 0, 0, 0}, pza[4] = {0, 0, 0, 0}, pah[4] = {0, 0, 0, 0};
#pragma unroll
    for (int m = 0; m < 4; ++m) {
#pragma unroll
        for (int q = 0; q < 4; ++q) {
            int row = rowb + m * 16 + q;
            bool ok = row < NT;
            int rowc = ok ? row : (NT - 1);
            float okf = ok ? 1.f : 0.f;
            float a = Aw[b * NT + rowc] * okf;
            const float* hrow = hsrc + ((size_t)b * NT + rowc) * ND;
#pragma unroll
            for (int n = 0; n < 4; ++n) {
                float hv = hrow[colb + n * 16] * okf;
                float o2 = acc[m][n][q] + b2c[n];
                pm[n] = fmaf(o2, hv, pm[n]);
                ps2[n] = fmaf(o2 * hv, hv, ps2[n]);
                pza[n] = fmaf(a, o2, pza[n]);
                pah[n] = fmaf(a, hv, pah[n]);
            }
        }
    }
#pragma unroll
    for (int n = 0; n < 4; ++n) {
        pm[n] += __shfl_xor(pm[n], 16); pm[n] += __shfl_xor(pm[n], 32);
        ps2[n] += __shfl_xor(ps2[n], 16); ps2[n] += __shfl_xor(ps2[n], 32);
        pza[n] += __shfl_xor(pza[n], 16); pza[n] += __shfl_xor(pza[n], 32);
        pah[n] += __shfl_xor(pah[n], 16); pah[n] += __shfl_xor(pah[n], 32);
        if (kg == 0) {
            int col = colb + n * 16;
            atomicAdd(&mup[b * ND + col], pm[n]);
            atomicAdd(&s2p[b * ND + col], ps2[n]);
            atomicAdd(&zab[b * ND + col], pza[n]);
            atomicAdd(&ahb[b * ND + col], pah[n]);
        }
    }
}

// ---------------- base GEMM: 2-term Ah*(Bh+Bl), single-buffered, XCD-swizzled ----------------
// A = h (f32, on-the-fly hi split), B = W1 hi/lo tiles, K=1536, N=1024; writes base(+biasb)
__global__ __launch_bounds__(256, 4) void k_gemm_base(
    const float* __restrict__ hsrc, const unsigned short* __restrict__ bt_h,
    const unsigned short* __restrict__ bt_l, const float* __restrict__ biasb,
    float* __restrict__ Out) {
    constexpr int KC = ND / 32;  // 48
    __shared__ unsigned short As[4096];
    __shared__ unsigned short Bh_s[4096];
    __shared__ unsigned short Bl_s[4096];
    // XCD swizzle: grid 12x8x8 = 768, chunk 96 = one b-plane per XCD
    int flat = blockIdx.x + 12 * (blockIdx.y + 8 * blockIdx.z);
    int swzf = (flat & 7) * 96 + (flat >> 3);
    int tr = swzf % 12, nt = (swzf / 12) % 8, b = swzf / 96;
    int tid = threadIdx.x;
    int lane = tid & 63, w = tid >> 6;
    int wr = w >> 1, wc = w & 1;
    int l15 = lane & 15, kg = lane >> 4;
    int sw = (l15 >> 1) & 3;
    f32x4 acc[4][4];
#pragma unroll
    for (int m = 0; m < 4; ++m)
#pragma unroll
        for (int n = 0; n < 4; ++n) acc[m][n] = (f32x4){0.f, 0.f, 0.f, 0.f};
    int aoff[4], boff[4];
#pragma unroll
    for (int m = 0; m < 4; ++m) aoff[m] = (wr * 64 + m * 16 + l15) * 32 + ((kg ^ sw) << 3);
#pragma unroll
    for (int n = 0; n < 4; ++n) boff[n] = (wc * 64 + n * 16 + l15) * 32 + ((kg ^ sw) << 3);

    const unsigned short* gbh = bt_h + ((size_t)nt * KC) * 4096 + lane * 8;
    const unsigned short* gbl = bt_l + ((size_t)nt * KC) * 4096 + lane * 8;

    int r2 = tid >> 1, quad = tid & 1;
    int arow = tr * 128 + r2;
    bool aok = arow < NT;
    int aswz = (r2 >> 1) & 3;
    const float* hp = hsrc + ((size_t)b * NT + arow) * ND + quad * 16;

    for (int kc = 0; kc < KC; ++kc) {
        // B: 16 segments (Bh 8, Bl 8), 4 per wave
#pragma unroll
        for (int c = 0; c < 4; ++c) {
            int seg = w * 4 + c;
            int part = seg & 7;
            const unsigned short* src =
                ((seg >> 3) == 0 ? gbh : gbl) + (size_t)kc * 4096 + part * 512;
            unsigned short* dst = ((seg >> 3) == 0 ? &Bh_s[0] : &Bl_s[0]) + part * 512;
            __builtin_amdgcn_global_load_lds(src, dst, 16, 0, 0);
        }
        // A: f32 load, hi-only split, LDS write
#pragma unroll
        for (int i = 0; i < 4; ++i) {
            int kk = quad * 16 + i * 4;
            float x0 = 0.f, x1 = 0.f, x2 = 0.f, x3 = 0.f;
            if (aok) {
                float4 v = *(const float4*)(hp + kc * 32 + i * 4);
                x0 = v.x; x1 = v.y; x2 = v.z; x3 = v.w;
            }
            int off = r2 * 32 + (((kk >> 3) ^ aswz) << 3) + (kk & 7);
            *(ushort4*)&As[off] = make_ushort4(bf_rne(x0), bf_rne(x1), bf_rne(x2), bf_rne(x3));
        }
        __syncthreads();
        bf16x8 af[4];
#pragma unroll
        for (int m = 0; m < 4; ++m) af[m] = *(const bf16x8*)&As[aoff[m]];
#pragma unroll
        for (int n = 0; n < 4; ++n) {
            bf16x8 bh = *(const bf16x8*)&Bh_s[boff[n]];
            bf16x8 bl = *(const bf16x8*)&Bl_s[boff[n]];
#pragma unroll
            for (int m = 0; m < 4; ++m) {
                acc[m][n] = __builtin_amdgcn_mfma_f32_16x16x32_bf16(af[m], bh, acc[m][n], 0, 0, 0);
                acc[m][n] = __builtin_amdgcn_mfma_f32_16x16x32_bf16(af[m], bl, acc[m][n], 0, 0, 0);
            }
        }
        __syncthreads();
    }

    int rowb = tr * 128 + wr * 64 + (kg << 2);
    int colb = nt * 128 + wc * 64 + l15;
#pragma unroll
    for (int m = 0; m < 4; ++m)
#pragma unroll
        for (int q = 0; q < 4; ++q) {
            int row = rowb + m * 16 + q;
            if (row < NT) {
                float* orow = Out + ((size_t)b * NT + row) * NP;
#pragma unroll
                for (int n = 0; n < 4; ++n)
                    orow[colb + n * 16] = acc[m][n][q] + biasb[b * NP + colb + n * 16];
            }
        }
}

// ---------------- per-iteration small kernels ----------------
// grid (4, 32), block 256
__global__ void k_cvec(const float* __restrict__ C, const float* __restrict__ Wc,
                       float* __restrict__ cvec) {
    int p = blockIdx.x * 256 + threadIdx.x;
    int d0 = blockIdx.y * 48, d1 = d0 + 48;
    float acc[NB];
#pragma unroll
    for (int b = 0; b < NB; ++b) acc[b] = 0.f;
    for (int d = d0; d < d1; ++d) {
        float wc = Wc[(size_t)d * NP + p];
#pragma unroll
        for (int b = 0; b < NB; ++b) acc[b] += C[b * ND + d] * wc;
    }
#pragma unroll
    for (int b = 0; b < NB; ++b) atomicAdd(&cvec[b * NP + p], acc[b]);
}

__global__ void k_softmax(const float* __restrict__ att, const float* __restrict__ emask,
                          const float* __restrict__ b2m, float* __restrict__ A) {
    __shared__ float red[256];
    int b = blockIdx.x, tid = threadIdx.x;
    float bm = b2m[0];
    const float* x = att + (size_t)b * NT;
    const float* em = emask + (size_t)b * NT;
    float* a = A + (size_t)b * NT;
    float mx = -3.4e38f;
    for (int t = tid; t < NT; t += 256) {
        float v = (em[t] > 0.5f) ? x[t] + bm : NEGINF;
        mx = fmaxf(mx, v);
    }
    red[tid] = mx; __syncthreads();
    for (int s = 128; s > 0; s >>= 1) {
        if (tid < s) red[tid] = fmaxf(red[tid], red[tid + s]);
        __syncthreads();
    }
    mx = red[0]; __syncthreads();
    float sm = 0.f;
    for (int t = tid; t < NT; t += 256) {
        float v = (em[t] > 0.5f) ? x[t] + bm : NEGINF;
        float e = expf(v - mx); a[t] = e; sm += e;
    }
    float s1 = block_reduce_sum(sm, red);
    float inv1 = 1.f / s1;
    float sm2 = 0.f;
    for (int t = tid; t < NT; t += 256) { float v = a[t] * inv1; a[t] = v; sm2 += v; }
    float s2 = block_reduce_sum(sm2, red);
    float inv2 = 1.f / (s2 + 1e-8f);
    for (int t = tid; t < NT; t += 256) a[t] *= inv2;
}

// parallel emb accumulation: grid 32, block 192
__global__ void k_embacc(const float* __restrict__ red4, const float* __restrict__ w0,
                         float* __restrict__ embt) {
    __shared__ float mus[NB][48], sgs[NB][48];
    int e = threadIdx.x;
    int d0 = blockIdx.x * 48;
    const float* mup = red4;
    const float* s2p = red4 + (size_t)NB * ND;
    for (int idx = e; idx < NB * 48; idx += 192) {
        int b = idx / 48, dd = idx % 48;
        float mu = mup[b * ND + d0 + dd];
        mus[b][dd] = mu;
        sgs[b][dd] = sqrtf(fmaxf(s2p[b * ND + d0 + dd] - mu * mu, 1e-8f));
    }
    __syncthreads();
    float acc[NB];
#pragma unroll
    for (int b = 0; b < NB; ++b) acc[b] = 0.f;
    for (int dd = 0; dd < 48; ++dd) {
        float wa = w0[(size_t)(d0 + dd) * NE + e];
        float wb = w0[(size_t)(ND + d0 + dd) * NE + e];
#pragma unroll
        for (int b = 0; b < NB; ++b)
            acc[b] += mus[b][dd] * wa + sgs[b][dd] * wb;
    }
#pragma unroll
    for (int b = 0; b < NB; ++b) atomicAdd(&embt[b * NE + e], acc[b]);
}

// C-update + stop prob + masked emb-norm write; grid NB, block 256
__global__ void k_tail2(const float* __restrict__ red4, const float* __restrict__ embt,
                        const float* __restrict__ b0, const float* __restrict__ Wstop,
                        const float* __restrict__ bstop, const float* __restrict__ thr,
                        float* __restrict__ Cb, float* __restrict__ stopf,
                        float* __restrict__ Eout, float* __restrict__ Pout, int iter) {
    __shared__ float red[256];
    __shared__ float liveflag;
    int b = blockIdx.x, tid = threadIdx.x;
    const float* Ahb = red4 + (size_t)2 * NB * ND + b * ND;
    const float* zAb = red4 + (size_t)3 * NB * ND + b * ND;
    float active = (stopf[b] > 0.5f) ? 0.f : 1.f;
    float dsum = 0.f;
    for (int d = tid; d < ND; d += 256) {
        float Cn = Cb[b * ND + d] + active * (Ahb[d] * (1.f / NT));
        Cb[b * ND + d] = Cn;
        dsum += zAb[d] * Wstop[d] + Cn * Wstop[ND + d];
    }
    float s = block_reduce_sum(dsum, red);
    if (tid == 0) {
        float logit = s + bstop[0];
        float p = 1.f / (1.f + expf(-logit));
        Pout[b * NITER + iter] = p;
        bool newly = p < thr[0];
        if (newly) stopf[b] = 1.f;
        liveflag = (active > 0.5f && !newly) ? 1.f : 0.f;
    }
    __syncthreads();
    float live = liveflag;
    float emb = (tid < NE) ? (embt[b * NE + tid] + b0[tid]) : 0.f;
    float nrm = block_reduce_sum(emb * emb, red);
    float sc = live / fmaxf(sqrtf(nrm), 1e-12f);
    if (tid < NE) Eout[((size_t)b * NITER + iter) * NE + tid] = emb * sc;
}

// ---------------- launch ----------------
extern "C" void kernel_launch(void* const* d_in, const int* in_sizes, int n_in,
                              void* d_out, int out_size, void* d_ws, size_t ws_size,
                              hipStream_t stream) {
    const float* h = (const float*)d_in[0];
    const float* W1 = (const float*)d_in[1];
    const float* Wc = (const float*)d_in[2];
    const float* W2 = (const float*)d_in[3];
    const float* b2 = (const float*)d_in[4];
    const float* w0 = (const float*)d_in[5];
    const float* b0 = (const float*)d_in[6];
    const float* Wstop = (const float*)d_in[7];
    const float* bstop = (const float*)d_in[8];
    const float* thr = (const float*)d_in[9];
    const float* C0 = (const float*)d_in[10];

    float* Eout = (float*)d_out;
    float* Pout = Eout + (size_t)NB * NITER * NE;

    char* wsb = (char*)d_ws;
    size_t off = 0;
    auto alloc = [&](size_t bytes) -> void* {
        void* p = wsb + off; off += (bytes + 15) & ~(size_t)15; return p;
    };

    float* base = (float*)alloc((size_t)NB * NT * NP * 4);
    unsigned short* rel_h = (unsigned short*)alloc((size_t)NB * 12 * 32 * 4096 * 2);
    unsigned short* w1t_h = (unsigned short*)alloc((size_t)8 * 48 * 4096 * 2);
    unsigned short* w1t_l = (unsigned short*)alloc((size_t)8 * 48 * 4096 * 2);
    unsigned short* w2t_h = (unsigned short*)alloc((size_t)12 * 32 * 4096 * 2);
    unsigned short* w2t_l = (unsigned short*)alloc((size_t)12 * 32 * 4096 * 2);
    float* mu0 = (float*)alloc((size_t)2 * NB * ND * 4);  // mu0 + sig0 contiguous
    float* sig0 = mu0 + NB * ND;
    float* emask = (float*)alloc(NB * NT * 4);
    float* biasb = (float*)alloc(NB * NP * 4);
    float* w2r = (float*)alloc(NP * 4);
    float* b2m = (float*)alloc(16);
    // zero-region: cvec | att | red4 | embt (contiguous, one memset per iteration)
    size_t zelems = (size_t)NB * NP + NB * NT + 4 * NB * ND + NB * NE;
    float* cvec = (float*)alloc(zelems * 4);
    float* att = cvec + NB * NP;
    float* red4 = att + NB * NT;
    float* mup = red4;
    float* s2p = red4 + NB * ND;
    float* zAb = red4 + 3 * NB * ND;
    float* Ahb = red4 + 2 * NB * ND;
    float* embt = red4 + 4 * NB * ND;
    float* Abuf = (float*)alloc(NB * NT * 4);
    float* Cb = (float*)alloc(NB * ND * 4);
    float* stopf = (float*)alloc(32);
    size_t zero_bytes = zelems * 4;

    // ---- pre-pass ----
    hipMemsetAsync(mu0, 0, (size_t)2 * NB * ND * 4, stream);
    hipMemsetAsync(biasb, 0, (size_t)NB * NP * 4, stream);
    k_colstats<<<dim3(ND / 256, NB, 12), 256, 0, stream>>>(h, mu0, sig0);
    k_stats_fin<<<dim3(NB * ND / 256), 256, 0, stream>>>(mu0, sig0);
    k_energy<<<dim3(NT, NB), 256, 0, stream>>>(h, emask);
    k_w2r<<<dim3(NP + 1), 256, 0, stream>>>(W2, b2, w2r, b2m);
    k_biasb<<<dim3(NP / 256, 8), 256, 0, stream>>>(W1, mu0, sig0, biasb);
    k_split_w<<<dim3(8, 48), 256, 0, stream>>>(W1, NP, 48, w1t_h, w1t_l);
    k_split_w<<<dim3(12, 32), 256, 0, stream>>>(W2, ND, 32, w2t_h, w2t_l);
    k_gemm_base<<<dim3(12, 8, NB), 256, 0, stream>>>(h, w1t_h, w1t_l, biasb, base);
    k_init<<<dim3(ND / 256, NB), 256, 0, stream>>>(Cb, C0, stopf);

    // ---- iterations ----
    for (int i = 0; i < NITER; ++i) {
        hipMemsetAsync(cvec, 0, zero_bytes, stream);
        k_cvec<<<dim3(4, 32), 256, 0, stream>>>(Cb, Wc, cvec);
        k_relu_att<<<dim3(12, 32, NB), 256, 0, stream>>>(base, cvec, w2r, rel_h, att);
        k_softmax<<<dim3(NB), 256, 0, stream>>>(att, emask, b2m, Abuf);
        k_gemm_relu<<<dim3(12, 12, NB), 256, 0, stream>>>(
            h, rel_h, w2t_h, b2, Abuf, mup, s2p, zAb, Ahb);
        k_embacc<<<dim3(32), 192, 0, stream>>>(red4, w0, embt);
        k_tail2<<<dim3(NB), 256, 0, stream>>>(red4, embt, b0, Wstop, bstop, thr,
                                              Cb, stopf, Eout, Pout, i);
    }
}